// Round 2
// baseline (8096.642 us; speedup 1.0000x reference)
//
#include <hip/hip_runtime.h>
#include <math.h>

#define NN 4096
#define FF 128
#define CD 100
#define OT_ITERS 20
#define NB 256
#define RPB 16
#define NBAR 48
#define RVAL (1.0f/4096.0f)

typedef unsigned int uint;

// ---------- bf16 helpers ----------
__device__ __forceinline__ float bflo(uint u){ return __uint_as_float(u << 16); }
__device__ __forceinline__ float bfhi(uint u){ return __uint_as_float(u & 0xFFFF0000u); }
__device__ __forceinline__ unsigned short f2bf(float x){
  uint u = __float_as_uint(x);
  u += 0x7FFFu + ((u >> 16) & 1u);
  return (unsigned short)(u >> 16);
}
__device__ __forceinline__ void unpack8(uint4 kk, float* e){
  e[0]=bflo(kk.x); e[1]=bfhi(kk.x); e[2]=bflo(kk.y); e[3]=bfhi(kk.y);
  e[4]=bflo(kk.z); e[5]=bfhi(kk.z); e[6]=bflo(kk.w); e[7]=bfhi(kk.w);
}

// ---------- wave/block reduce helpers (wave = 64) ----------
__device__ __forceinline__ float waveSum(float v){
#pragma unroll
  for (int o=32;o>0;o>>=1) v += __shfl_down(v,o);
  return v;
}
__device__ __forceinline__ float waveMax(float v){
#pragma unroll
  for (int o=32;o>0;o>>=1) v = fmaxf(v,__shfl_down(v,o));
  return v;
}
__device__ __forceinline__ float waveMin(float v){
#pragma unroll
  for (int o=32;o>0;o>>=1) v = fminf(v,__shfl_down(v,o));
  return v;
}
__device__ __forceinline__ float blkMax(float v, float* red){
  v = waveMax(v);
  if ((threadIdx.x&63)==0) red[threadIdx.x>>6] = v;
  __syncthreads();
  float r = fmaxf(fmaxf(red[0],red[1]),fmaxf(red[2],red[3]));
  __syncthreads();
  return r;
}
__device__ __forceinline__ float blkMin(float v, float* red){
  v = waveMin(v);
  if ((threadIdx.x&63)==0) red[threadIdx.x>>6] = v;
  __syncthreads();
  float r = fminf(fminf(red[0],red[1]),fminf(red[2],red[3]));
  __syncthreads();
  return r;
}
__device__ __forceinline__ float blkSum(float v, float* red){
  v = waveSum(v);
  if ((threadIdx.x&63)==0) red[threadIdx.x>>6] = v;
  __syncthreads();
  float r = red[0]+red[1]+red[2]+red[3];
  __syncthreads();
  return r;
}

// ---------- grid barrier (2-level, per-instance counters, pre-zeroed) ----------
__device__ __forceinline__ void gridbar(int* gcnt, int* rcnt, int* rel, int inst){
  __syncthreads();
  if (threadIdx.x == 0){
    __threadfence();
    int g = blockIdx.x >> 4;
    if (atomicAdd(&gcnt[inst*16 + g], 1) == 15){
      if (atomicAdd(&rcnt[inst], 1) == 15){
        __threadfence();
        __hip_atomic_store(&rel[inst], 1, __ATOMIC_RELAXED, __HIP_MEMORY_SCOPE_AGENT);
      }
    }
    while (__hip_atomic_load(&rel[inst], __ATOMIC_RELAXED, __HIP_MEMORY_SCOPE_AGENT) == 0){
      __builtin_amdgcn_s_sleep(2);
    }
    __threadfence();
  }
  __syncthreads();
}

// ---------- embed GEMM: out[4096x128] = A[4096xK] @ W[Kx128] + b ----------
__global__ __launch_bounds__(256) void embed_gemm(const float* __restrict__ A,
                                                  const float* __restrict__ W,
                                                  const float* __restrict__ bias,
                                                  float* __restrict__ out, int K)
{
  __shared__ float As[16][64];
  __shared__ float Ws[64][128];
  const int tid = threadIdx.x;
  const int tx = tid & 127, ty = tid >> 7;
  const int row0 = blockIdx.x * 16;
  float acc[8];
#pragma unroll
  for (int r=0;r<8;++r) acc[r]=0.f;
  for (int k0 = 0; k0 < K; k0 += 64) {
    {
      int r = tid >> 4, c4 = tid & 15;
      *(float4*)&As[r][c4*4] = *(const float4*)&A[(size_t)(row0+r)*K + k0 + c4*4];
    }
#pragma unroll
    for (int it=0; it<8; ++it) {
      int f4 = tid + it*256;
      int kk = f4 >> 5, c4 = f4 & 31;
      *(float4*)&Ws[kk][c4*4] = *(const float4*)&W[(size_t)(k0+kk)*FF + c4*4];
    }
    __syncthreads();
    for (int kk=0; kk<64; kk+=4) {
      float a[8][4];
#pragma unroll
      for (int rr=0;rr<8;++rr) *(float4*)a[rr] = *(const float4*)&As[ty*8+rr][kk];
#pragma unroll
      for (int q=0;q<4;++q) {
        float b = Ws[kk+q][tx];
#pragma unroll
        for (int rr=0;rr<8;++rr) acc[rr] += a[rr][q]*b;
      }
    }
    __syncthreads();
  }
#pragma unroll
  for (int rr=0;rr<8;++rr)
    out[(size_t)(row0+ty*8+rr)*FF + tx] = acc[rr] + bias[tx];
}

// ---------- row l2 normalize (d=128) ----------
__global__ __launch_bounds__(128) void l2norm_rows(float* __restrict__ f)
{
  __shared__ float sred[2];
  int i = blockIdx.x, t = threadIdx.x;
  float v = f[(size_t)i*FF + t];
  float s = waveSum(v*v);
  int lane = t & 63, wid = t >> 6;
  if (lane==0) sred[wid]=s;
  __syncthreads();
  float tot = sred[0]+sred[1];
  f[(size_t)i*FF + t] = v / sqrtf(tot);
}

// ---------- softmax rows of l[4096x100] -> S, w = ||S_row|| ----------
__global__ __launch_bounds__(128) void softmax_rows(const float* __restrict__ l,
                                                    float* __restrict__ S,
                                                    float* __restrict__ w)
{
  __shared__ float sm[2], ss[2], sq[2];
  int i = blockIdx.x, t = threadIdx.x;
  int lane = t & 63, wid = t >> 6;
  float x = (t < CD) ? l[(size_t)i*CD + t] : -3.4e38f;
  float m = waveMax(x);
  if (lane==0) sm[wid]=m;
  __syncthreads();
  m = fmaxf(sm[0], sm[1]);
  float e = (t < CD) ? __expf(x - m) : 0.f;
  float s = waveSum(e);
  if (lane==0) ss[wid]=s;
  __syncthreads();
  float tot = ss[0]+ss[1];
  float sv = e / tot;
  if (t < CD) S[(size_t)i*CD + t] = sv;
  float q = waveSum(sv*sv);
  if (lane==0) sq[wid]=q;
  __syncthreads();
  if (t==0) w[i] = sqrtf(sq[0]+sq[1]);
}

// ---------- knn: idx[i][0]=i plus top-7 cosine neighbors ----------
__global__ __launch_bounds__(256) void knn_topk(const float* __restrict__ S,
                                                const float* __restrict__ w,
                                                int* __restrict__ idx)
{
  __shared__ float si[128];
  __shared__ float redv[256];
  __shared__ int   redi[256];
  int i = blockIdx.x, tid = threadIdx.x;
  if (tid < 128) si[tid] = (tid < CD) ? S[(size_t)i*CD + tid] : 0.f;
  __syncthreads();
  float wi = w[i];
  float bv[7]; int bi[7];
#pragma unroll
  for (int m=0;m<7;++m){ bv[m]=-3.4e38f; bi[m]=-1; }
  const float4* si4 = (const float4*)si;
  for (int j = tid; j < NN; j += 256) {
    if (j == i) continue;
    const float4* sj4 = (const float4*)&S[(size_t)j*CD];
    float dot = 0.f;
#pragma unroll
    for (int k=0;k<25;++k) {
      float4 a = si4[k], b = sj4[k];
      dot += a.x*b.x + a.y*b.y + a.z*b.z + a.w*b.w;
    }
    float cv = dot / fmaxf(wi * w[j], 1e-7f);
    if (cv > bv[6]) {
      int m = 6;
      while (m > 0 && cv > bv[m-1]) { bv[m]=bv[m-1]; bi[m]=bi[m-1]; --m; }
      bv[m]=cv; bi[m]=j;
    }
  }
  if (tid==0) idx[(size_t)i*8] = i;
  for (int m=0;m<7;++m) {
    redv[tid]=bv[0]; redi[tid]=tid;
    __syncthreads();
    for (int s=128;s>=1;s>>=1) {
      if (tid < s) {
        if (redv[tid+s] > redv[tid]) { redv[tid]=redv[tid+s]; redi[tid]=redi[tid+s]; }
      }
      __syncthreads();
    }
    int wt = redi[0];
    if (tid == wt) {
      idx[(size_t)i*8 + 1 + m] = bi[0];
#pragma unroll
      for (int q=0;q<6;++q){ bv[q]=bv[q+1]; bi[q]=bi[q+1]; }
      bv[6]=-3.4e38f; bi[6]=-1;
    }
    __syncthreads();
  }
}

// ---------- encoder: out = l2norm(concat(h, mean(h[idx])) @ W + b) ----------
__global__ __launch_bounds__(128) void encoder_kernel(const float* __restrict__ h,
                                                      const int* __restrict__ idx,
                                                      const float* __restrict__ W,
                                                      const float* __restrict__ bias,
                                                      float* __restrict__ out)
{
  __shared__ float hin[256];
  __shared__ float sred[2];
  int i = blockIdx.x, t = threadIdx.x;
  float hv = h[(size_t)i*FF + t];
  float agg = 0.f;
#pragma unroll
  for (int m=0;m<8;++m) agg += h[(size_t)idx[i*8+m]*FF + t];
  agg *= 0.125f;
  hin[t] = hv; hin[FF + t] = agg;
  __syncthreads();
  float acc = bias[t];
  for (int k=0;k<256;++k) acc += hin[k] * W[(size_t)k*FF + t];
  float s = waveSum(acc*acc);
  int lane = t & 63, wid = t >> 6;
  if (lane==0) sred[wid]=s;
  __syncthreads();
  float tot = sred[0]+sred[1];
  out[(size_t)i*FF + t] = acc / sqrtf(tot);
}

// ---------- C[4096x4096](bf16) = A[4096x128] @ B[4096x128]^T ----------
__global__ __launch_bounds__(256) void gemm_btb(const float* __restrict__ A,
                                                const float* __restrict__ B,
                                                unsigned short* __restrict__ C)
{
  __shared__ float As[64][68];
  __shared__ float Bs[64][68];
  const int tid = threadIdx.x;
  const int tc = tid & 15, tr = tid >> 4;
  const int i0 = blockIdx.y * 64, j0 = blockIdx.x * 64;
  float acc[4][4];
#pragma unroll
  for (int a=0;a<4;++a)
#pragma unroll
    for (int b=0;b<4;++b) acc[a][b]=0.f;
  for (int k0 = 0; k0 < FF; k0 += 64) {
#pragma unroll
    for (int it=0; it<4; ++it) {
      int f4 = tid + it*256;
      int r = f4 >> 4, c4 = f4 & 15;
      *(float4*)&As[r][c4*4] = *(const float4*)&A[(size_t)(i0+r)*FF + k0 + c4*4];
      float4 bvv = *(const float4*)&B[(size_t)(j0+r)*FF + k0 + c4*4];
      Bs[c4*4+0][r] = bvv.x; Bs[c4*4+1][r] = bvv.y;
      Bs[c4*4+2][r] = bvv.z; Bs[c4*4+3][r] = bvv.w;
    }
    __syncthreads();
    for (int kk=0; kk<64; kk+=4) {
      float a[4][4];
#pragma unroll
      for (int q=0;q<4;++q) *(float4*)a[q] = *(const float4*)&As[tr*4+q][kk];
#pragma unroll
      for (int t=0;t<4;++t) {
        float4 b = *(const float4*)&Bs[kk+t][tc*4];
#pragma unroll
        for (int rr=0;rr<4;++rr) {
          float av = a[rr][t];
          acc[rr][0] += av*b.x; acc[rr][1] += av*b.y;
          acc[rr][2] += av*b.z; acc[rr][3] += av*b.w;
        }
      }
    }
    __syncthreads();
  }
#pragma unroll
  for (int rr=0;rr<4;++rr) {
    union { unsigned short us[4]; uint2 u2; } pk;
#pragma unroll
    for (int c=0;c<4;++c) pk.us[c] = f2bf(acc[rr][c]);
    *(uint2*)&C[(size_t)(i0+tr*4+rr)*NN + j0 + tc*4] = pk.u2;
  }
}

// ---------- per-ot init: v=1, barriers=0, acc=0 ----------
__global__ void ot_init(float* __restrict__ v, int* __restrict__ barmem,
                        double* __restrict__ accd)
{
  int t = blockIdx.x*256 + threadIdx.x;
  if (t < NN) v[t] = 1.f;
  if (t < NBAR*18) barmem[t] = 0;
  if (t == 0) *accd = 0.0;
}

// ---------- persistent sinkhorn: stats -> K build -> 20 iters -> loss/P ----------
__global__ __launch_bounds__(256) void sinkhorn_persist(
    unsigned short* __restrict__ Kb,
    float* __restrict__ v, float* __restrict__ part,
    float* __restrict__ bstats, int* __restrict__ barmem,
    double* __restrict__ accd, int finalot,
    float* __restrict__ Pout, float* __restrict__ Mout)
{
  __shared__ float red[4];
  __shared__ float rowmx[RPB];
  __shared__ float urow[RPB];
  __shared__ float sgmin, sscale;

  int* gcnt = barmem;
  int* rcnt = barmem + 16*NBAR;
  int* rel  = barmem + 17*NBAR;

  const int b = blockIdx.x, i0 = b*RPB, t = threadIdx.x;

  // ---- pass 1: per-row max + block min over own bf16 M0 rows ----
  float bmn = 3.4e38f;
  for (int r=0;r<RPB;++r){
    const uint4* row = (const uint4*)(Kb + (size_t)(i0+r)*NN);
    float rmx = -3.4e38f, rmn = 3.4e38f;
#pragma unroll
    for (int s=0;s<2;++s){
      float e[8]; unpack8(row[t + s*256], e);
#pragma unroll
      for (int k=0;k<8;++k){ rmx = fmaxf(rmx, e[k]); rmn = fminf(rmn, e[k]); }
    }
    float rm = blkMax(rmx, red);
    if (t==0) rowmx[r] = rm;
    bmn = fminf(bmn, rmn);
  }
  {
    float bm = blkMin(bmn, red);
    if (t==0){ bstats[b*2] = bm; bstats[b*2+1] = -3.4e38f; }
    // block max = max of rowmx
    __syncthreads();
    if (t==0){
      float m = rowmx[0];
#pragma unroll
      for (int r=1;r<RPB;++r) m = fmaxf(m, rowmx[r]);
      bstats[b*2+1] = m;
    }
  }
  gridbar(gcnt, rcnt, rel, 0);
  // ---- global min/max (redundant per block) ----
  {
    float2 p = ((const float2*)bstats)[t];  // t<256=NB
    float gmn = blkMin(p.x, red);
    float gmx = blkMax(p.y, red);
    if (t==0){ sgmin = gmn; sscale = 1.f/(gmx - gmn); }
    __syncthreads();
  }
  const float gmin = sgmin, scale = sscale;

  // ---- pass 2: in-place K = exp((M0 - rowmax)*scale); optional M output ----
  for (int r=0;r<RPB;++r){
    const size_t base = (size_t)(i0+r)*NN;
    uint4* row = (uint4*)(Kb + base);
    float rmx = rowmx[r];
#pragma unroll
    for (int s=0;s<2;++s){
      int ji = t + s*256;
      float e[8]; unpack8(row[ji], e);
      union { unsigned short us[8]; uint4 u4; } pk;
#pragma unroll
      for (int k=0;k<8;++k) pk.us[k] = f2bf(__expf((e[k]-rmx)*scale));
      row[ji] = pk.u4;
      if (finalot){
        int j = ji*8;
#pragma unroll
        for (int k=0;k<8;++k) Mout[base + j + k] = (e[k]-gmin)*scale;
      }
    }
  }
  __syncthreads();

  const float4* v4 = (const float4*)v;
  const int arow = t >> 4, q = t & 15;
  const uint4* Krow = (const uint4*)(Kb + (size_t)(i0+arow)*NN);

  // ---- 20 sinkhorn iterations ----
  for (int it=0; it<OT_ITERS; ++it){
    // phase A: u_i = R / (K v)_i  (own rows)
    {
      float sum = 0.f;
#pragma unroll 4
      for (int s=0;s<32;++s){
        int j8 = q + s*16;
        uint4 kk = Krow[j8];
        float4 va = v4[j8*2], vb = v4[j8*2+1];
        sum += bflo(kk.x)*va.x + bfhi(kk.x)*va.y + bflo(kk.y)*va.z + bfhi(kk.y)*va.w
             + bflo(kk.z)*vb.x + bfhi(kk.z)*vb.y + bflo(kk.w)*vb.z + bfhi(kk.w)*vb.w;
      }
#pragma unroll
      for (int m=8;m>=1;m>>=1) sum += __shfl_xor(sum, m, 16);
      if (q==0) urow[arow] = RVAL / sum;
    }
    __syncthreads();
    // phase B: part[b][j] = sum_r K[r][j]*u_r
#pragma unroll
    for (int s=0;s<2;++s){
      int j = t*8 + s*2048;
      float a0=0,a1=0,a2=0,a3=0,a4=0,a5=0,a6=0,a7=0;
#pragma unroll
      for (int r=0;r<RPB;++r){
        uint4 kk = *(const uint4*)(Kb + (size_t)(i0+r)*NN + j);
        float ur = urow[r];
        a0 += bflo(kk.x)*ur; a1 += bfhi(kk.x)*ur;
        a2 += bflo(kk.y)*ur; a3 += bfhi(kk.y)*ur;
        a4 += bflo(kk.z)*ur; a5 += bfhi(kk.z)*ur;
        a6 += bflo(kk.w)*ur; a7 += bfhi(kk.w)*ur;
      }
      float4* pp = (float4*)(part + (size_t)b*NN + j);
      float4 o1; o1.x=a0;o1.y=a1;o1.z=a2;o1.w=a3;
      float4 o2; o2.x=a4;o2.y=a5;o2.z=a6;o2.w=a7;
      pp[0]=o1; pp[1]=o2;
    }
    gridbar(gcnt, rcnt, rel, 1+2*it);
    // phase C: v_j = R / sum_b part[b][j]  (own 16 columns)
    {
      int j = i0 + (t>>4);
      int bb = t & 15;
      float s2 = 0.f;
#pragma unroll
      for (int s=0;s<16;++s) s2 += part[(size_t)(bb + s*16)*NN + j];
#pragma unroll
      for (int m=8;m>=1;m>>=1) s2 += __shfl_xor(s2, m, 16);
      if (bb==0) v[j] = RVAL / s2;
    }
    gridbar(gcnt, rcnt, rel, 2+2*it);
  }

  // ---- final: y = K v ; P = K_ij v_j / y_i ; loss += ||P - I||^2 ----
  {
    float sum = 0.f;
#pragma unroll 4
    for (int s=0;s<32;++s){
      int j8 = q + s*16;
      uint4 kk = Krow[j8];
      float4 va = v4[j8*2], vb = v4[j8*2+1];
      sum += bflo(kk.x)*va.x + bfhi(kk.x)*va.y + bflo(kk.y)*va.z + bfhi(kk.y)*va.w
           + bflo(kk.z)*vb.x + bfhi(kk.z)*vb.y + bflo(kk.w)*vb.z + bfhi(kk.w)*vb.w;
    }
#pragma unroll
    for (int m=8;m>=1;m>>=1) sum += __shfl_xor(sum, m, 16);
    if (q==0) urow[arow] = sum;   // y_i
  }
  __syncthreads();
  {
    const float invy = 1.f / urow[arow];
    const int idiag = i0 + arow;
    float local = 0.f;
    for (int s=0;s<32;++s){
      int j8 = q + s*16;
      int j = j8*8;
      uint4 kk = Krow[j8];
      float4 va = v4[j8*2], vb = v4[j8*2+1];
      float p[8];
      p[0]=bflo(kk.x)*va.x*invy; p[1]=bfhi(kk.x)*va.y*invy;
      p[2]=bflo(kk.y)*va.z*invy; p[3]=bfhi(kk.y)*va.w*invy;
      p[4]=bflo(kk.z)*vb.x*invy; p[5]=bfhi(kk.z)*vb.y*invy;
      p[6]=bflo(kk.w)*vb.z*invy; p[7]=bfhi(kk.w)*vb.w*invy;
      if (finalot){
#pragma unroll
        for (int k=0;k<8;++k) Pout[(size_t)idiag*NN + j + k] = p[k];
      }
#pragma unroll
      for (int k=0;k<8;++k){
        float d = p[k] - ((j+k)==idiag ? 1.f : 0.f);
        local += d*d;
      }
    }
    float tot = blkSum(local, red);
    if (t==0) atomicAdd(accd, (double)tot);
  }
}

__global__ void lossfin(const double* __restrict__ acc, float* __restrict__ outslot)
{
  if (threadIdx.x==0) *outslot = (float)sqrt(*acc);
}

__global__ void sumloss(float* __restrict__ out)
{
  if (threadIdx.x==0) out[0] = out[1]+out[2]+out[3]+out[4];
}

extern "C" void kernel_launch(void* const* d_in, const int* in_sizes, int n_in,
                              void* d_out, int out_size, void* d_ws, size_t ws_size,
                              hipStream_t stream)
{
  (void)in_sizes; (void)n_in; (void)out_size; (void)ws_size;
  const float* f_s  = (const float*)d_in[1];
  const float* l_s  = (const float*)d_in[2];
  const float* f_t  = (const float*)d_in[3];
  const float* l_t  = (const float*)d_in[4];
  const float* W_es = (const float*)d_in[5];
  const float* b_es = (const float*)d_in[6];
  const float* W_et = (const float*)d_in[7];
  const float* b_et = (const float*)d_in[8];
  const float* W_gs = (const float*)d_in[9];
  const float* b_gs = (const float*)d_in[10];
  const float* W_gt = (const float*)d_in[11];
  const float* b_gt = (const float*)d_in[12];
  float* out = (float*)d_out;

  double* accd = (double*)d_ws;
  float* base = (float*)d_ws + 4;
  float* f_es = base; base += NN*FF;
  float* f_et = base; base += NN*FF;
  float* f_gs = base; base += NN*FF;
  float* f_gt = base; base += NN*FF;
  float* S_s  = base; base += NN*CD;
  float* S_t  = base; base += NN*CD;
  float* w_s  = base; base += NN;
  float* w_t  = base; base += NN;
  int* idx_s  = (int*)base; base += NN*8;
  int* idx_t  = (int*)base; base += NN*8;
  float* bstats = base; base += 512;
  float* v    = base; base += NN;
  float* part = base; base += (size_t)NB*NN;
  int* barmem = (int*)base; base += 1024;
  unsigned short* Kbuf = (unsigned short*)base;  // NN*NN bf16 = 32MB

  float* Pout_final = out + 5;
  float* Mout_final = out + 5 + (size_t)NN*NN;

  auto run_ot = [&](const float* ft, const float* fs, int slot, int finalot){
    gemm_btb<<<dim3(64,64),256,0,stream>>>(ft, fs, Kbuf);
    ot_init<<<16,256,0,stream>>>(v, barmem, accd);
    sinkhorn_persist<<<NB,256,0,stream>>>(Kbuf, v, part, bstats, barmem, accd,
                                          finalot,
                                          finalot ? Pout_final : (float*)nullptr,
                                          finalot ? Mout_final : (float*)nullptr);
    lossfin<<<1,1,0,stream>>>(accd, out + slot);
  };

  // embeddings
  embed_gemm<<<256,256,0,stream>>>(f_s, W_es, b_es, f_es, 8192);
  embed_gemm<<<256,256,0,stream>>>(f_t, W_et, b_et, f_et, 8192);
  l2norm_rows<<<NN,128,0,stream>>>(f_es);
  l2norm_rows<<<NN,128,0,stream>>>(f_et);

  // loss_e = ot(f_et, f_es) -> slot 1
  run_ot(f_et, f_es, 1, 0);

  // knn + encoders
  softmax_rows<<<NN,128,0,stream>>>(l_s, S_s, w_s);
  softmax_rows<<<NN,128,0,stream>>>(l_t, S_t, w_t);
  knn_topk<<<NN,256,0,stream>>>(S_s, w_s, idx_s);
  knn_topk<<<NN,256,0,stream>>>(S_t, w_t, idx_t);
  encoder_kernel<<<NN,128,0,stream>>>(f_es, idx_s, W_gs, b_gs, f_gs);
  encoder_kernel<<<NN,128,0,stream>>>(f_et, idx_t, W_gt, b_gt, f_gt);

  // loss_ge = ot(f_gt, f_es) -> slot 3
  run_ot(f_gt, f_es, 3, 0);
  // loss_eg = ot(f_et, f_gt) -> slot 4
  run_ot(f_et, f_gt, 4, 0);
  // loss_g = ot(f_gt, f_gs) -> slot 2, writes P and M
  run_ot(f_gt, f_gs, 2, 1);

  sumloss<<<1,1,0,stream>>>(out);
}

// Round 3
// 2739.714 us; speedup vs baseline: 2.9553x; 2.9553x over previous
//
#include <hip/hip_runtime.h>
#include <math.h>

#define NN 4096
#define FF 128
#define CD 100
#define OT_ITERS 20
#define RVAL (1.0f/4096.0f)

typedef unsigned int uint;

// ---------- bf16 helpers ----------
__device__ __forceinline__ float bflo(uint u){ return __uint_as_float(u << 16); }
__device__ __forceinline__ float bfhi(uint u){ return __uint_as_float(u & 0xFFFF0000u); }
__device__ __forceinline__ float bf2f(unsigned short s){ return __uint_as_float((uint)s << 16); }
__device__ __forceinline__ unsigned short f2bf(float x){
  uint u = __float_as_uint(x);
  u += 0x7FFFu + ((u >> 16) & 1u);
  return (unsigned short)(u >> 16);
}
__device__ __forceinline__ void unpack8(uint4 kk, float* e){
  e[0]=bflo(kk.x); e[1]=bfhi(kk.x); e[2]=bflo(kk.y); e[3]=bfhi(kk.y);
  e[4]=bflo(kk.z); e[5]=bfhi(kk.z); e[6]=bflo(kk.w); e[7]=bfhi(kk.w);
}

// ---------- wave/block reduce helpers (wave = 64) ----------
__device__ __forceinline__ float waveSum(float v){
#pragma unroll
  for (int o=32;o>0;o>>=1) v += __shfl_down(v,o);
  return v;
}
__device__ __forceinline__ float waveMax(float v){
#pragma unroll
  for (int o=32;o>0;o>>=1) v = fmaxf(v,__shfl_down(v,o));
  return v;
}
__device__ __forceinline__ float waveMin(float v){
#pragma unroll
  for (int o=32;o>0;o>>=1) v = fminf(v,__shfl_down(v,o));
  return v;
}
__device__ __forceinline__ float blkSum(float v, float* red){
  v = waveSum(v);
  if ((threadIdx.x&63)==0) red[threadIdx.x>>6] = v;
  __syncthreads();
  float r = red[0]+red[1]+red[2]+red[3];
  __syncthreads();
  return r;
}

// ---------- embed GEMM: out[4096x128] = A[4096xK] @ W[Kx128] + b ----------
__global__ __launch_bounds__(256) void embed_gemm(const float* __restrict__ A,
                                                  const float* __restrict__ W,
                                                  const float* __restrict__ bias,
                                                  float* __restrict__ out, int K)
{
  __shared__ float As[16][64];
  __shared__ float Ws[64][128];
  const int tid = threadIdx.x;
  const int tx = tid & 127, ty = tid >> 7;
  const int row0 = blockIdx.x * 16;
  float acc[8];
#pragma unroll
  for (int r=0;r<8;++r) acc[r]=0.f;
  for (int k0 = 0; k0 < K; k0 += 64) {
    {
      int r = tid >> 4, c4 = tid & 15;
      *(float4*)&As[r][c4*4] = *(const float4*)&A[(size_t)(row0+r)*K + k0 + c4*4];
    }
#pragma unroll
    for (int it=0; it<8; ++it) {
      int f4 = tid + it*256;
      int kk = f4 >> 5, c4 = f4 & 31;
      *(float4*)&Ws[kk][c4*4] = *(const float4*)&W[(size_t)(k0+kk)*FF + c4*4];
    }
    __syncthreads();
    for (int kk=0; kk<64; kk+=4) {
      float a[8][4];
#pragma unroll
      for (int rr=0;rr<8;++rr) *(float4*)a[rr] = *(const float4*)&As[ty*8+rr][kk];
#pragma unroll
      for (int q=0;q<4;++q) {
        float b = Ws[kk+q][tx];
#pragma unroll
        for (int rr=0;rr<8;++rr) acc[rr] += a[rr][q]*b;
      }
    }
    __syncthreads();
  }
#pragma unroll
  for (int rr=0;rr<8;++rr)
    out[(size_t)(row0+ty*8+rr)*FF + tx] = acc[rr] + bias[tx];
}

// ---------- row l2 normalize (d=128) ----------
__global__ __launch_bounds__(128) void l2norm_rows(float* __restrict__ f)
{
  __shared__ float sred[2];
  int i = blockIdx.x, t = threadIdx.x;
  float v = f[(size_t)i*FF + t];
  float s = waveSum(v*v);
  int lane = t & 63, wid = t >> 6;
  if (lane==0) sred[wid]=s;
  __syncthreads();
  float tot = sred[0]+sred[1];
  f[(size_t)i*FF + t] = v / sqrtf(tot);
}

// ---------- softmax rows of l[4096x100] -> S, w = ||S_row|| ----------
__global__ __launch_bounds__(128) void softmax_rows(const float* __restrict__ l,
                                                    float* __restrict__ S,
                                                    float* __restrict__ w)
{
  __shared__ float sm[2], ss[2], sq[2];
  int i = blockIdx.x, t = threadIdx.x;
  int lane = t & 63, wid = t >> 6;
  float x = (t < CD) ? l[(size_t)i*CD + t] : -3.4e38f;
  float m = waveMax(x);
  if (lane==0) sm[wid]=m;
  __syncthreads();
  m = fmaxf(sm[0], sm[1]);
  float e = (t < CD) ? __expf(x - m) : 0.f;
  float s = waveSum(e);
  if (lane==0) ss[wid]=s;
  __syncthreads();
  float tot = ss[0]+ss[1];
  float sv = e / tot;
  if (t < CD) S[(size_t)i*CD + t] = sv;
  float q = waveSum(sv*sv);
  if (lane==0) sq[wid]=q;
  __syncthreads();
  if (t==0) w[i] = sqrtf(sq[0]+sq[1]);
}

// ---------- cos matrix: D[i][j] = (S_i . S_j)/max(w_i w_j, eps), diag = -2 ----------
__global__ __launch_bounds__(256) void cos_gemm(const float* __restrict__ S,
                                                const float* __restrict__ w,
                                                float* __restrict__ D)
{
  __shared__ float As[64][108];
  __shared__ float Bs[100][68];
  const int tid = threadIdx.x;
  const int tc = tid & 15, tr = tid >> 4;
  const int i0 = blockIdx.y*64, j0 = blockIdx.x*64;
  for (int f = tid; f < 64*25; f += 256){
    int r = f/25, c4 = f%25;
    *(float4*)&As[r][c4*4] = *(const float4*)&S[(size_t)(i0+r)*CD + c4*4];
  }
  for (int f = tid; f < 64*25; f += 256){
    int r = f/25, c4 = f%25;
    float4 bv = *(const float4*)&S[(size_t)(j0+r)*CD + c4*4];
    Bs[c4*4+0][r]=bv.x; Bs[c4*4+1][r]=bv.y; Bs[c4*4+2][r]=bv.z; Bs[c4*4+3][r]=bv.w;
  }
  __syncthreads();
  float acc[4][4];
#pragma unroll
  for (int a=0;a<4;++a)
#pragma unroll
    for (int b=0;b<4;++b) acc[a][b]=0.f;
  for (int kk=0; kk<100; kk+=4){
    float a[4][4];
#pragma unroll
    for (int q=0;q<4;++q) *(float4*)a[q] = *(const float4*)&As[tr*4+q][kk];
#pragma unroll
    for (int t4=0;t4<4;++t4){
      float4 b = *(const float4*)&Bs[kk+t4][tc*4];
#pragma unroll
      for (int rr=0;rr<4;++rr){
        float av = a[rr][t4];
        acc[rr][0] += av*b.x; acc[rr][1] += av*b.y;
        acc[rr][2] += av*b.z; acc[rr][3] += av*b.w;
      }
    }
  }
  float wi[4], wj[4];
#pragma unroll
  for (int q=0;q<4;++q){ wi[q] = w[i0+tr*4+q]; wj[q] = w[j0+tc*4+q]; }
#pragma unroll
  for (int rr=0;rr<4;++rr){
    int i = i0+tr*4+rr;
    float4 o;
    float* op = (float*)&o;
#pragma unroll
    for (int cc=0;cc<4;++cc){
      int j = j0+tc*4+cc;
      float val = acc[rr][cc] / fmaxf(wi[rr]*wj[cc], 1e-7f);
      op[cc] = (i==j) ? -2.f : val;
    }
    *(float4*)&D[(size_t)i*NN + j0 + tc*4] = o;
  }
}

// ---------- top-7 select per row of D; idx[i][0] = i ----------
__global__ __launch_bounds__(256) void knn_select(const float* __restrict__ D,
                                                  int* __restrict__ idx)
{
  __shared__ float redv[256];
  __shared__ int   redi[256];
  int i = blockIdx.x, tid = threadIdx.x;
  float bv[7]; int bi[7];
#pragma unroll
  for (int m=0;m<7;++m){ bv[m]=-3.4e38f; bi[m]=-1; }
  const float4* row4 = (const float4*)&D[(size_t)i*NN];
#pragma unroll
  for (int s=0;s<4;++s){
    int j4 = tid + s*256;
    float4 vv = row4[j4];
    float cv[4] = {vv.x, vv.y, vv.z, vv.w};
#pragma unroll
    for (int q=0;q<4;++q){
      if (cv[q] > bv[6]) {
        int m = 6;
        while (m > 0 && cv[q] > bv[m-1]) { bv[m]=bv[m-1]; bi[m]=bi[m-1]; --m; }
        bv[m]=cv[q]; bi[m]=j4*4+q;
      }
    }
  }
  if (tid==0) idx[(size_t)i*8] = i;
  for (int m=0;m<7;++m) {
    redv[tid]=bv[0]; redi[tid]=tid;
    __syncthreads();
    for (int s=128;s>=1;s>>=1) {
      if (tid < s) {
        if (redv[tid+s] > redv[tid]) { redv[tid]=redv[tid+s]; redi[tid]=redi[tid+s]; }
      }
      __syncthreads();
    }
    int wt = redi[0];
    if (tid == wt) {
      idx[(size_t)i*8 + 1 + m] = bi[0];
#pragma unroll
      for (int q=0;q<6;++q){ bv[q]=bv[q+1]; bi[q]=bi[q+1]; }
      bv[6]=-3.4e38f; bi[6]=-1;
    }
    __syncthreads();
  }
}

// ---------- encoder: out = l2norm(concat(h, mean(h[idx])) @ W + b) ----------
__global__ __launch_bounds__(128) void encoder_kernel(const float* __restrict__ h,
                                                      const int* __restrict__ idx,
                                                      const float* __restrict__ W,
                                                      const float* __restrict__ bias,
                                                      float* __restrict__ out)
{
  __shared__ float hin[256];
  __shared__ float sred[2];
  int i = blockIdx.x, t = threadIdx.x;
  float hv = h[(size_t)i*FF + t];
  float agg = 0.f;
#pragma unroll
  for (int m=0;m<8;++m) agg += h[(size_t)idx[i*8+m]*FF + t];
  agg *= 0.125f;
  hin[t] = hv; hin[FF + t] = agg;
  __syncthreads();
  float acc = bias[t];
  for (int k=0;k<256;++k) acc += hin[k] * W[(size_t)k*FF + t];
  float s = waveSum(acc*acc);
  int lane = t & 63, wid = t >> 6;
  if (lane==0) sred[wid]=s;
  __syncthreads();
  float tot = sred[0]+sred[1];
  out[(size_t)i*FF + t] = acc / sqrtf(tot);
}

// ---------- C[4096x4096](bf16) = A[4096x128] @ B[4096x128]^T ----------
__global__ __launch_bounds__(256) void gemm_btb(const float* __restrict__ A,
                                                const float* __restrict__ B,
                                                unsigned short* __restrict__ C)
{
  __shared__ float As[64][68];
  __shared__ float Bs[64][68];
  const int tid = threadIdx.x;
  const int tc = tid & 15, tr = tid >> 4;
  const int i0 = blockIdx.y * 64, j0 = blockIdx.x * 64;
  float acc[4][4];
#pragma unroll
  for (int a=0;a<4;++a)
#pragma unroll
    for (int b=0;b<4;++b) acc[a][b]=0.f;
  for (int k0 = 0; k0 < FF; k0 += 64) {
#pragma unroll
    for (int it=0; it<4; ++it) {
      int f4 = tid + it*256;
      int r = f4 >> 4, c4 = f4 & 15;
      *(float4*)&As[r][c4*4] = *(const float4*)&A[(size_t)(i0+r)*FF + k0 + c4*4];
      float4 bvv = *(const float4*)&B[(size_t)(j0+r)*FF + k0 + c4*4];
      Bs[c4*4+0][r] = bvv.x; Bs[c4*4+1][r] = bvv.y;
      Bs[c4*4+2][r] = bvv.z; Bs[c4*4+3][r] = bvv.w;
    }
    __syncthreads();
    for (int kk=0; kk<64; kk+=4) {
      float a[4][4];
#pragma unroll
      for (int q=0;q<4;++q) *(float4*)a[q] = *(const float4*)&As[tr*4+q][kk];
#pragma unroll
      for (int t=0;t<4;++t) {
        float4 b = *(const float4*)&Bs[kk+t][tc*4];
#pragma unroll
        for (int rr=0;rr<4;++rr) {
          float av = a[rr][t];
          acc[rr][0] += av*b.x; acc[rr][1] += av*b.y;
          acc[rr][2] += av*b.z; acc[rr][3] += av*b.w;
        }
      }
    }
    __syncthreads();
  }
#pragma unroll
  for (int rr=0;rr<4;++rr) {
    union { unsigned short us[4]; uint2 u2; } pk;
#pragma unroll
    for (int c=0;c<4;++c) pk.us[c] = f2bf(acc[rr][c]);
    *(uint2*)&C[(size_t)(i0+tr*4+rr)*NN + j0 + tc*4] = pk.u2;
  }
}

// ---------- batched: per-row max/min over bf16 M0 ----------
__global__ __launch_bounds__(256) void rowstat_b(const unsigned short* __restrict__ Kbase,
                                                 float* __restrict__ rmax,
                                                 float* __restrict__ rmin)
{
  __shared__ float r1[4], r2[4];
  int m = blockIdx.y, i = blockIdx.x, t = threadIdx.x;
  const uint4* row = (const uint4*)(Kbase + ((size_t)m*NN + i)*NN);
  float mx=-3.4e38f, mn=3.4e38f;
#pragma unroll
  for (int s=0;s<2;++s){
    float e[8]; unpack8(row[t + s*256], e);
#pragma unroll
    for (int k=0;k<8;++k){ mx = fmaxf(mx,e[k]); mn = fminf(mn,e[k]); }
  }
  mx = waveMax(mx); mn = waveMin(mn);
  int lane = t & 63, wid = t >> 6;
  if (lane==0){ r1[wid]=mx; r2[wid]=mn; }
  __syncthreads();
  if (t==0){
    rmax[(size_t)m*NN+i] = fmaxf(fmaxf(r1[0],r1[1]),fmaxf(r1[2],r1[3]));
    rmin[(size_t)m*NN+i] = fminf(fminf(r2[0],r2[1]),fminf(r2[2],r2[3]));
  }
}

__global__ __launch_bounds__(256) void greduce_b(const float* __restrict__ rmax,
                                                 const float* __restrict__ rmin,
                                                 float* __restrict__ stat)
{
  __shared__ float r1[4], r2[4];
  int m = blockIdx.x, t = threadIdx.x;
  float mx=-3.4e38f, mn=3.4e38f;
  for (int i=t; i<NN; i+=256){
    mx = fmaxf(mx, rmax[(size_t)m*NN+i]);
    mn = fminf(mn, rmin[(size_t)m*NN+i]);
  }
  mx = waveMax(mx); mn = waveMin(mn);
  int lane = t & 63, wid = t >> 6;
  if (lane==0){ r1[wid]=mx; r2[wid]=mn; }
  __syncthreads();
  if (t==0){
    float gmx = fmaxf(fmaxf(r1[0],r1[1]),fmaxf(r1[2],r1[3]));
    float gmn = fminf(fminf(r2[0],r2[1]),fminf(r2[2],r2[3]));
    stat[m*2]   = gmn;
    stat[m*2+1] = 1.f/(gmx-gmn);
  }
}

// ---------- batched in-place K = exp((M0 - rowmax)*scale); M output for finalm ----------
__global__ __launch_bounds__(256) void transform_b(unsigned short* __restrict__ Kbase,
                                                   const float* __restrict__ rmax,
                                                   const float* __restrict__ stat,
                                                   float* __restrict__ Mout, int finalm)
{
  int m = blockIdx.y;
  const float gmin = stat[m*2], scale = stat[m*2+1];
  uint4* Km = (uint4*)(Kbase + (size_t)m*NN*NN);
  const bool wM = (m==finalm) && (Mout != nullptr);
  const int total8 = (NN*NN)/8;
  for (int f = blockIdx.x*256 + threadIdx.x; f < total8; f += 256*256){
    int i = f >> 9;
    float rm = rmax[(size_t)m*NN + i];
    float e[8]; unpack8(Km[f], e);
    union { unsigned short us[8]; uint4 u4; } pk;
#pragma unroll
    for (int k=0;k<8;++k) pk.us[k] = f2bf(__expf((e[k]-rm)*scale));
    Km[f] = pk.u4;
    if (wM){
      float4 o1, o2;
      o1.x=(e[0]-gmin)*scale; o1.y=(e[1]-gmin)*scale; o1.z=(e[2]-gmin)*scale; o1.w=(e[3]-gmin)*scale;
      o2.x=(e[4]-gmin)*scale; o2.y=(e[5]-gmin)*scale; o2.z=(e[6]-gmin)*scale; o2.w=(e[7]-gmin)*scale;
      float4* mp = (float4*)(Mout + (size_t)f*8);
      mp[0]=o1; mp[1]=o2;
    }
  }
}

__global__ void ot_init_b(float* __restrict__ v, double* __restrict__ accd, int nmat)
{
  int g = blockIdx.x*256 + threadIdx.x;
  if (g < nmat*NN) v[g] = 1.f;
  if (g < nmat) accd[g] = 0.0;
}

// ---------- batched u_i = R/(K v)_i ----------
__global__ __launch_bounds__(256) void rowmv_b(const unsigned short* __restrict__ Kbase,
                                               const float* __restrict__ vv,
                                               float* __restrict__ uu)
{
  __shared__ float red[4];
  int m = blockIdx.y, i = blockIdx.x, t = threadIdx.x;
  const uint4* row = (const uint4*)(Kbase + ((size_t)m*NN + i)*NN);
  const float4* v4 = (const float4*)(vv + (size_t)m*NN);
  float s = 0.f;
#pragma unroll
  for (int ss=0;ss<2;++ss){
    int j8 = t + ss*256;
    uint4 kk = row[j8];
    float4 va = v4[j8*2], vb = v4[j8*2+1];
    s += bflo(kk.x)*va.x + bfhi(kk.x)*va.y + bflo(kk.y)*va.z + bfhi(kk.y)*va.w
       + bflo(kk.z)*vb.x + bfhi(kk.z)*vb.y + bflo(kk.w)*vb.z + bfhi(kk.w)*vb.w;
  }
  float tot = blkSum(s, red);
  if (t==0) uu[(size_t)m*NN + i] = RVAL / tot;
}

// ---------- batched column partials: part[m][chunk][j] = sum K[i][j]*u[i] ----------
__global__ __launch_bounds__(256) void colpart_b(const unsigned short* __restrict__ Kbase,
                                                 const float* __restrict__ uu,
                                                 float* __restrict__ part)
{
  __shared__ float su[128];
  int m = blockIdx.z;
  int j = blockIdx.x*256 + threadIdx.x;
  int r0 = blockIdx.y*128;
  if (threadIdx.x < 128) su[threadIdx.x] = uu[(size_t)m*NN + r0 + threadIdx.x];
  __syncthreads();
  const unsigned short* Km = Kbase + (size_t)m*NN*NN;
  float s = 0.f;
#pragma unroll 4
  for (int ii=0; ii<128; ++ii)
    s += bf2f(Km[(size_t)(r0+ii)*NN + j]) * su[ii];
  part[((size_t)m*32 + blockIdx.y)*NN + j] = s;
}

__global__ __launch_bounds__(256) void colfin_b(const float* __restrict__ part,
                                                float* __restrict__ vv)
{
  int m = blockIdx.y;
  int j = blockIdx.x*256 + threadIdx.x;
  float s = 0.f;
#pragma unroll
  for (int b=0;b<32;++b) s += part[((size_t)m*32 + b)*NN + j];
  vv[(size_t)m*NN + j] = RVAL / s;
}

// ---------- fused final: y = Kv ; P = K v_j / y ; acc += ||P - I||^2 ----------
__global__ __launch_bounds__(256) void loss_b(const unsigned short* __restrict__ Kbase,
                                              const float* __restrict__ vv,
                                              double* __restrict__ accd,
                                              float* __restrict__ Pout, int finalm)
{
  __shared__ float red[4];
  int m = blockIdx.y, i = blockIdx.x, t = threadIdx.x;
  const uint4* row = (const uint4*)(Kbase + ((size_t)m*NN + i)*NN);
  const float4* v4 = (const float4*)(vv + (size_t)m*NN);
  float e[16], vr[16];
#pragma unroll
  for (int ss=0;ss<2;++ss){
    int j8 = t + ss*256;
    unpack8(row[j8], &e[ss*8]);
    float4 va = v4[j8*2], vb = v4[j8*2+1];
    vr[ss*8+0]=va.x; vr[ss*8+1]=va.y; vr[ss*8+2]=va.z; vr[ss*8+3]=va.w;
    vr[ss*8+4]=vb.x; vr[ss*8+5]=vb.y; vr[ss*8+6]=vb.z; vr[ss*8+7]=vb.w;
  }
  float s = 0.f;
#pragma unroll
  for (int k=0;k<16;++k) s += e[k]*vr[k];
  float y = blkSum(s, red);
  float invy = 1.f / y;
  const bool wp = (m==finalm) && (Pout != nullptr);
  float local = 0.f;
#pragma unroll
  for (int ss=0;ss<2;++ss){
    int j0 = (t + ss*256)*8;
    float p[8];
#pragma unroll
    for (int k=0;k<8;++k) p[k] = e[ss*8+k]*vr[ss*8+k]*invy;
    if (wp){
      float4 o1, o2;
      o1.x=p[0]; o1.y=p[1]; o1.z=p[2]; o1.w=p[3];
      o2.x=p[4]; o2.y=p[5]; o2.z=p[6]; o2.w=p[7];
      float4* pp = (float4*)(Pout + (size_t)i*NN + j0);
      pp[0]=o1; pp[1]=o2;
    }
#pragma unroll
    for (int k=0;k<8;++k){
      float d = p[k] - ((j0+k)==i ? 1.f : 0.f);
      local += d*d;
    }
  }
  float tot = blkSum(local, red);
  if (t==0) atomicAdd(&accd[m], (double)tot);
}

__global__ void lossfin(const double* __restrict__ acc, float* __restrict__ outslot)
{
  if (threadIdx.x==0) *outslot = (float)sqrt(*acc);
}

__global__ void sumloss(float* __restrict__ out)
{
  if (threadIdx.x==0) out[0] = out[1]+out[2]+out[3]+out[4];
}

extern "C" void kernel_launch(void* const* d_in, const int* in_sizes, int n_in,
                              void* d_out, int out_size, void* d_ws, size_t ws_size,
                              hipStream_t stream)
{
  (void)in_sizes; (void)n_in; (void)out_size;
  const float* f_s  = (const float*)d_in[1];
  const float* l_s  = (const float*)d_in[2];
  const float* f_t  = (const float*)d_in[3];
  const float* l_t  = (const float*)d_in[4];
  const float* W_es = (const float*)d_in[5];
  const float* b_es = (const float*)d_in[6];
  const float* W_et = (const float*)d_in[7];
  const float* b_et = (const float*)d_in[8];
  const float* W_gs = (const float*)d_in[9];
  const float* b_gs = (const float*)d_in[10];
  const float* W_gt = (const float*)d_in[11];
  const float* b_gt = (const float*)d_in[12];
  float* out = (float*)d_out;

  char* ws = (char*)d_ws;
  size_t off = 0;
  auto alloc = [&](size_t nbytes)->void*{
    off = (off + 255) & ~(size_t)255;
    void* p = ws + off; off += nbytes; return p;
  };
  double* accd = (double*)alloc(4*sizeof(double));
  float* f_es = (float*)alloc((size_t)NN*FF*4);
  float* f_et = (float*)alloc((size_t)NN*FF*4);
  float* f_gs = (float*)alloc((size_t)NN*FF*4);
  float* f_gt = (float*)alloc((size_t)NN*FF*4);
  float* S_s  = (float*)alloc((size_t)NN*CD*4);
  float* S_t  = (float*)alloc((size_t)NN*CD*4);
  float* w_s  = (float*)alloc(NN*4);
  float* w_t  = (float*)alloc(NN*4);
  int*   idx_s= (int*)alloc(NN*8*4);
  int*   idx_t= (int*)alloc(NN*8*4);
  float* rmax = (float*)alloc((size_t)4*NN*4);
  float* rmin = (float*)alloc((size_t)4*NN*4);
  float* stat = (float*)alloc(64);
  float* v    = (float*)alloc((size_t)4*NN*4);
  float* u    = (float*)alloc((size_t)4*NN*4);
  float* part = (float*)alloc((size_t)4*32*NN*4);
  off = (off + 255) & ~(size_t)255;
  unsigned short* Kb = (unsigned short*)(ws + off);
  size_t remain = (ws_size > off) ? ws_size - off : 0;
  const size_t matB = (size_t)NN*NN*2;           // 32 MB per bf16 matrix
  const int big = (remain >= 4*matB) ? 1 : 0;    // need 128 MB for 4-way batch

  float* Pout_final = out + 5;
  float* Mout_final = out + 5 + (size_t)NN*NN;

  // ---- embeddings ----
  embed_gemm<<<256,256,0,stream>>>(f_s, W_es, b_es, f_es, 8192);
  embed_gemm<<<256,256,0,stream>>>(f_t, W_et, b_et, f_et, 8192);
  l2norm_rows<<<NN,128,0,stream>>>(f_es);
  l2norm_rows<<<NN,128,0,stream>>>(f_et);

  // ---- knn path (uses K region as scratch for fp32 cos matrices) ----
  softmax_rows<<<NN,128,0,stream>>>(l_s, S_s, w_s);
  softmax_rows<<<NN,128,0,stream>>>(l_t, S_t, w_t);
  if (big) {
    float* D_s = (float*)Kb;                       // 64 MB = mats 0,1
    float* D_t = (float*)(Kb + 2*(size_t)NN*NN);   // 64 MB = mats 2,3
    cos_gemm<<<dim3(64,64),256,0,stream>>>(S_s, w_s, D_s);
    cos_gemm<<<dim3(64,64),256,0,stream>>>(S_t, w_t, D_t);
    knn_select<<<NN,256,0,stream>>>(D_s, idx_s);
    knn_select<<<NN,256,0,stream>>>(D_t, idx_t);
  } else {
    float* Db = (float*)Kb;                        // sequential reuse, 64 MB
    cos_gemm<<<dim3(64,64),256,0,stream>>>(S_s, w_s, Db);
    knn_select<<<NN,256,0,stream>>>(Db, idx_s);
    cos_gemm<<<dim3(64,64),256,0,stream>>>(S_t, w_t, Db);
    knn_select<<<NN,256,0,stream>>>(Db, idx_t);
  }
  encoder_kernel<<<NN,128,0,stream>>>(f_es, idx_s, W_gs, b_gs, f_gs);
  encoder_kernel<<<NN,128,0,stream>>>(f_et, idx_t, W_gt, b_gt, f_gt);

  // ---- batched OT ----
  const float* ftab[4] = { f_et, f_gt, f_et, f_gt };
  const float* fsab[4] = { f_es, f_es, f_gt, f_gs };
  const int slotab[4]  = { 1, 3, 4, 2 };

  auto run_batch = [&](int m0, int nmat, int finalm){
    for (int m=0;m<nmat;++m)
      gemm_btb<<<dim3(64,64),256,0,stream>>>(ftab[m0+m], fsab[m0+m], Kb + (size_t)m*NN*NN);
    rowstat_b<<<dim3(NN,nmat),256,0,stream>>>(Kb, rmax, rmin);
    greduce_b<<<nmat,256,0,stream>>>(rmax, rmin, stat);
    transform_b<<<dim3(256,nmat),256,0,stream>>>(Kb, rmax, stat,
        (finalm>=0)?Mout_final:(float*)nullptr, finalm);
    ot_init_b<<<(4*NN+255)/256,256,0,stream>>>(v, accd, nmat);
    for (int it=0; it<OT_ITERS; ++it){
      rowmv_b<<<dim3(NN,nmat),256,0,stream>>>(Kb, v, u);
      colpart_b<<<dim3(16,32,nmat),256,0,stream>>>(Kb, u, part);
      colfin_b<<<dim3(16,nmat),256,0,stream>>>(part, v);
    }
    loss_b<<<dim3(NN,nmat),256,0,stream>>>(Kb, v, accd,
        (finalm>=0)?Pout_final:(float*)nullptr, finalm);
    for (int m=0;m<nmat;++m)
      lossfin<<<1,1,0,stream>>>(accd+m, out + slotab[m0+m]);
  };

  if (big) {
    run_batch(0, 4, 3);
  } else {
    run_batch(0, 2, -1);
    run_batch(2, 2, 1);
  }

  sumloss<<<1,1,0,stream>>>(out);
}

// Round 4
// 1866.661 us; speedup vs baseline: 4.3375x; 1.4677x over previous
//
#include <hip/hip_runtime.h>
#include <math.h>

#define NN 4096
#define FF 128
#define CD 100
#define OT_ITERS 20
#define RVAL (1.0f/4096.0f)
#define EK 8192
#define KS 8

typedef unsigned int uint;
typedef __attribute__((ext_vector_type(8))) short bf16x8;
typedef __attribute__((ext_vector_type(4))) float f32x4;

// ---------- bf16 helpers ----------
__device__ __forceinline__ float bflo(uint u){ return __uint_as_float(u << 16); }
__device__ __forceinline__ float bfhi(uint u){ return __uint_as_float(u & 0xFFFF0000u); }
__device__ __forceinline__ float bf2f(unsigned short s){ return __uint_as_float((uint)s << 16); }
__device__ __forceinline__ unsigned short f2bf(float x){
  uint u = __float_as_uint(x);
  u += 0x7FFFu + ((u >> 16) & 1u);
  return (unsigned short)(u >> 16);
}
__device__ __forceinline__ void unpack8(uint4 kk, float* e){
  e[0]=bflo(kk.x); e[1]=bfhi(kk.x); e[2]=bflo(kk.y); e[3]=bfhi(kk.y);
  e[4]=bflo(kk.z); e[5]=bfhi(kk.z); e[6]=bflo(kk.w); e[7]=bfhi(kk.w);
}

// ---------- wave/block reduce helpers (wave = 64) ----------
__device__ __forceinline__ float waveSum(float v){
#pragma unroll
  for (int o=32;o>0;o>>=1) v += __shfl_down(v,o);
  return v;
}
__device__ __forceinline__ float waveMax(float v){
#pragma unroll
  for (int o=32;o>0;o>>=1) v = fmaxf(v,__shfl_down(v,o));
  return v;
}
__device__ __forceinline__ float waveMin(float v){
#pragma unroll
  for (int o=32;o>0;o>>=1) v = fminf(v,__shfl_down(v,o));
  return v;
}
__device__ __forceinline__ float blkSum(float v, float* red){
  v = waveSum(v);
  if ((threadIdx.x&63)==0) red[threadIdx.x>>6] = v;
  __syncthreads();
  float r = red[0]+red[1]+red[2]+red[3];
  __syncthreads();
  return r;
}

// ---------- W transpose+convert: Wt[n][k] bf16 from W[k][n] fp32 ----------
__global__ __launch_bounds__(256) void transposeW(const float* __restrict__ W,
                                                  unsigned short* __restrict__ Wt)
{
  __shared__ unsigned short T[128][72];
  const int k0 = blockIdx.x*64, tid = threadIdx.x;
#pragma unroll
  for (int it=0; it<8; ++it){
    int f = tid + it*256;
    int r = f >> 5, c4 = f & 31;
    float4 v = *(const float4*)&W[(size_t)(k0+r)*FF + c4*4];
    T[c4*4+0][r]=f2bf(v.x); T[c4*4+1][r]=f2bf(v.y);
    T[c4*4+2][r]=f2bf(v.z); T[c4*4+3][r]=f2bf(v.w);
  }
  __syncthreads();
#pragma unroll
  for (int it=0; it<4; ++it){
    int f = tid + it*256;
    int n = f >> 3, c8 = f & 7;
    *(uint4*)&Wt[(size_t)n*EK + k0 + c8*8] = *(uint4*)&T[n][c8*8];
  }
}

// ---------- MFMA embed GEMM (split-K): part[ks][4096][128] ----------
// grid (64, KS); A fp32 [4096][8192] converted to bf16 on the fly; Wt bf16 [128][8192]
__global__ __launch_bounds__(256) void embed_mfma(const float* __restrict__ A,
                                                  const unsigned short* __restrict__ Wt,
                                                  float* __restrict__ part)
{
  __shared__ unsigned short Al[64][72];
  __shared__ unsigned short Wl[128][72];
  const int tid = threadIdx.x;
  const int m0 = blockIdx.x * 64;
  const int kc = blockIdx.y * (EK/KS);
  const int w = tid >> 6, l = tid & 63;
  const int wr = w >> 1, wc = w & 1;          // wave 2x2 grid: 32 rows x 64 cols each
  const int lrow = l & 15, lk = (l >> 4) * 8;
  f32x4 acc[2][4];
#pragma unroll
  for (int mi=0;mi<2;++mi)
#pragma unroll
    for (int ni=0;ni<4;++ni) acc[mi][ni] = (f32x4){0.f,0.f,0.f,0.f};

  for (int k0 = kc; k0 < kc + EK/KS; k0 += 64) {
#pragma unroll
    for (int it = 0; it < 4; ++it) {           // A: 64x64 fp32 -> bf16
      int f = tid + it*256;
      int r = f >> 4, c4 = f & 15;
      float4 a4 = *(const float4*)&A[(size_t)(m0+r)*EK + k0 + c4*4];
      union { unsigned short us[4]; uint2 u2; } pk;
      pk.us[0]=f2bf(a4.x); pk.us[1]=f2bf(a4.y); pk.us[2]=f2bf(a4.z); pk.us[3]=f2bf(a4.w);
      *(uint2*)&Al[r][c4*4] = pk.u2;
    }
#pragma unroll
    for (int it = 0; it < 4; ++it) {           // Wt: 128 rows x 64 k bf16
      int f = tid + it*256;
      int r = f >> 3, c8 = f & 7;
      *(uint4*)&Wl[r][c8*8] = *(const uint4*)&Wt[(size_t)r*EK + k0 + c8*8];
    }
    __syncthreads();
#pragma unroll
    for (int ksub = 0; ksub < 2; ++ksub) {
      bf16x8 af[2], bfr[4];
#pragma unroll
      for (int mi=0;mi<2;++mi) af[mi] = *(bf16x8*)&Al[wr*32+mi*16+lrow][ksub*32+lk];
#pragma unroll
      for (int ni=0;ni<4;++ni) bfr[ni] = *(bf16x8*)&Wl[wc*64+ni*16+lrow][ksub*32+lk];
#pragma unroll
      for (int mi=0;mi<2;++mi)
#pragma unroll
        for (int ni=0;ni<4;++ni)
          acc[mi][ni] = __builtin_amdgcn_mfma_f32_16x16x32_bf16(af[mi], bfr[ni], acc[mi][ni], 0,0,0);
    }
    __syncthreads();
  }
  // D layout: row=(l>>4)*4+r, col=l&15
#pragma unroll
  for (int mi=0;mi<2;++mi)
#pragma unroll
    for (int ni=0;ni<4;++ni)
#pragma unroll
      for (int r=0;r<4;++r) {
        int row = m0 + wr*32 + mi*16 + (l>>4)*4 + r;
        int col = wc*64 + ni*16 + lrow;
        part[((size_t)blockIdx.y*NN + row)*FF + col] = acc[mi][ni][r];
      }
}

// ---------- reduce split-K partials + bias + l2norm ----------
__global__ __launch_bounds__(128) void reduce_l2(const float* __restrict__ part,
                                                 const float* __restrict__ bias,
                                                 float* __restrict__ out)
{
  __shared__ float red[2];
  int i = blockIdx.x, t = threadIdx.x;
  float s = bias[t];
#pragma unroll
  for (int ks=0; ks<KS; ++ks) s += part[((size_t)ks*NN + i)*FF + t];
  float q = waveSum(s*s);
  if ((t&63)==0) red[t>>6]=q;
  __syncthreads();
  out[(size_t)i*FF+t] = s / sqrtf(red[0]+red[1]);
}

// ---------- softmax rows of l[4096x100] -> S, w = ||S_row|| ----------
__global__ __launch_bounds__(128) void softmax_rows(const float* __restrict__ l,
                                                    float* __restrict__ S,
                                                    float* __restrict__ w)
{
  __shared__ float sm[2], ss[2], sq[2];
  int i = blockIdx.x, t = threadIdx.x;
  int lane = t & 63, wid = t >> 6;
  float x = (t < CD) ? l[(size_t)i*CD + t] : -3.4e38f;
  float m = waveMax(x);
  if (lane==0) sm[wid]=m;
  __syncthreads();
  m = fmaxf(sm[0], sm[1]);
  float e = (t < CD) ? __expf(x - m) : 0.f;
  float s = waveSum(e);
  if (lane==0) ss[wid]=s;
  __syncthreads();
  float tot = ss[0]+ss[1];
  float sv = e / tot;
  if (t < CD) S[(size_t)i*CD + t] = sv;
  float q = waveSum(sv*sv);
  if (lane==0) sq[wid]=q;
  __syncthreads();
  if (t==0) w[i] = sqrtf(sq[0]+sq[1]);
}

// ---------- cos matrix: D[i][j] = (S_i . S_j)/max(w_i w_j, eps), diag = -2 ----------
__global__ __launch_bounds__(256) void cos_gemm(const float* __restrict__ S,
                                                const float* __restrict__ w,
                                                float* __restrict__ D)
{
  __shared__ float As[64][108];
  __shared__ float Bs[100][68];
  const int tid = threadIdx.x;
  const int tc = tid & 15, tr = tid >> 4;
  const int i0 = blockIdx.y*64, j0 = blockIdx.x*64;
  for (int f = tid; f < 64*25; f += 256){
    int r = f/25, c4 = f%25;
    *(float4*)&As[r][c4*4] = *(const float4*)&S[(size_t)(i0+r)*CD + c4*4];
  }
  for (int f = tid; f < 64*25; f += 256){
    int r = f/25, c4 = f%25;
    float4 bv = *(const float4*)&S[(size_t)(j0+r)*CD + c4*4];
    Bs[c4*4+0][r]=bv.x; Bs[c4*4+1][r]=bv.y; Bs[c4*4+2][r]=bv.z; Bs[c4*4+3][r]=bv.w;
  }
  __syncthreads();
  float acc[4][4];
#pragma unroll
  for (int a=0;a<4;++a)
#pragma unroll
    for (int b=0;b<4;++b) acc[a][b]=0.f;
  for (int kk=0; kk<100; kk+=4){
    float a[4][4];
#pragma unroll
    for (int q=0;q<4;++q) *(float4*)a[q] = *(const float4*)&As[tr*4+q][kk];
#pragma unroll
    for (int t4=0;t4<4;++t4){
      float4 b = *(const float4*)&Bs[kk+t4][tc*4];
#pragma unroll
      for (int rr=0;rr<4;++rr){
        float av = a[rr][t4];
        acc[rr][0] += av*b.x; acc[rr][1] += av*b.y;
        acc[rr][2] += av*b.z; acc[rr][3] += av*b.w;
      }
    }
  }
  float wi[4], wj[4];
#pragma unroll
  for (int q=0;q<4;++q){ wi[q] = w[i0+tr*4+q]; wj[q] = w[j0+tc*4+q]; }
#pragma unroll
  for (int rr=0;rr<4;++rr){
    int i = i0+tr*4+rr;
    float4 o;
    float* op = (float*)&o;
#pragma unroll
    for (int cc=0;cc<4;++cc){
      int j = j0+tc*4+cc;
      float val = acc[rr][cc] / fmaxf(wi[rr]*wj[cc], 1e-7f);
      op[cc] = (i==j) ? -2.f : val;
    }
    *(float4*)&D[(size_t)i*NN + j0 + tc*4] = o;
  }
}

// ---------- top-7 select per row of D; idx[i][0] = i ----------
__global__ __launch_bounds__(256) void knn_select(const float* __restrict__ D,
                                                  int* __restrict__ idx)
{
  __shared__ float redv[256];
  __shared__ int   redi[256];
  int i = blockIdx.x, tid = threadIdx.x;
  float bv[7]; int bi[7];
#pragma unroll
  for (int m=0;m<7;++m){ bv[m]=-3.4e38f; bi[m]=-1; }
  const float4* row4 = (const float4*)&D[(size_t)i*NN];
#pragma unroll
  for (int s=0;s<4;++s){
    int j4 = tid + s*256;
    float4 vv = row4[j4];
    float cv[4] = {vv.x, vv.y, vv.z, vv.w};
#pragma unroll
    for (int q=0;q<4;++q){
      if (cv[q] > bv[6]) {
        int m = 6;
        while (m > 0 && cv[q] > bv[m-1]) { bv[m]=bv[m-1]; bi[m]=bi[m-1]; --m; }
        bv[m]=cv[q]; bi[m]=j4*4+q;
      }
    }
  }
  if (tid==0) idx[(size_t)i*8] = i;
  for (int m=0;m<7;++m) {
    redv[tid]=bv[0]; redi[tid]=tid;
    __syncthreads();
    for (int s=128;s>=1;s>>=1) {
      if (tid < s) {
        if (redv[tid+s] > redv[tid]) { redv[tid]=redv[tid+s]; redi[tid]=redi[tid+s]; }
      }
      __syncthreads();
    }
    int wt = redi[0];
    if (tid == wt) {
      idx[(size_t)i*8 + 1 + m] = bi[0];
#pragma unroll
      for (int q=0;q<6;++q){ bv[q]=bv[q+1]; bi[q]=bi[q+1]; }
      bv[6]=-3.4e38f; bi[6]=-1;
    }
    __syncthreads();
  }
}

// ---------- encoder: out = l2norm(concat(h, mean(h[idx])) @ W + b) ----------
__global__ __launch_bounds__(128) void encoder_kernel(const float* __restrict__ h,
                                                      const int* __restrict__ idx,
                                                      const float* __restrict__ W,
                                                      const float* __restrict__ bias,
                                                      float* __restrict__ out)
{
  __shared__ float hin[256];
  __shared__ float sred[2];
  int i = blockIdx.x, t = threadIdx.x;
  float hv = h[(size_t)i*FF + t];
  float agg = 0.f;
#pragma unroll
  for (int m=0;m<8;++m) agg += h[(size_t)idx[i*8+m]*FF + t];
  agg *= 0.125f;
  hin[t] = hv; hin[FF + t] = agg;
  __syncthreads();
  float acc = bias[t];
  for (int k=0;k<256;++k) acc += hin[k] * W[(size_t)k*FF + t];
  float s = waveSum(acc*acc);
  int lane = t & 63, wid = t >> 6;
  if (lane==0) sred[wid]=s;
  __syncthreads();
  float tot = sred[0]+sred[1];
  out[(size_t)i*FF + t] = acc / sqrtf(tot);
}

// ---------- C[4096x4096](bf16) = A[4096x128] @ B[4096x128]^T ----------
__global__ __launch_bounds__(256) void gemm_btb(const float* __restrict__ A,
                                                const float* __restrict__ B,
                                                unsigned short* __restrict__ C)
{
  __shared__ float As[64][68];
  __shared__ float Bs[64][68];
  const int tid = threadIdx.x;
  const int tc = tid & 15, tr = tid >> 4;
  const int i0 = blockIdx.y * 64, j0 = blockIdx.x * 64;
  float acc[4][4];
#pragma unroll
  for (int a=0;a<4;++a)
#pragma unroll
    for (int b=0;b<4;++b) acc[a][b]=0.f;
  for (int k0 = 0; k0 < FF; k0 += 64) {
#pragma unroll
    for (int it=0; it<4; ++it) {
      int f4 = tid + it*256;
      int r = f4 >> 4, c4 = f4 & 15;
      *(float4*)&As[r][c4*4] = *(const float4*)&A[(size_t)(i0+r)*FF + k0 + c4*4];
      float4 bvv = *(const float4*)&B[(size_t)(j0+r)*FF + k0 + c4*4];
      Bs[c4*4+0][r] = bvv.x; Bs[c4*4+1][r] = bvv.y;
      Bs[c4*4+2][r] = bvv.z; Bs[c4*4+3][r] = bvv.w;
    }
    __syncthreads();
    for (int kk=0; kk<64; kk+=4) {
      float a[4][4];
#pragma unroll
      for (int q=0;q<4;++q) *(float4*)a[q] = *(const float4*)&As[tr*4+q][kk];
#pragma unroll
      for (int t=0;t<4;++t) {
        float4 b = *(const float4*)&Bs[kk+t][tc*4];
#pragma unroll
        for (int rr=0;rr<4;++rr) {
          float av = a[rr][t];
          acc[rr][0] += av*b.x; acc[rr][1] += av*b.y;
          acc[rr][2] += av*b.z; acc[rr][3] += av*b.w;
        }
      }
    }
    __syncthreads();
  }
#pragma unroll
  for (int rr=0;rr<4;++rr) {
    union { unsigned short us[4]; uint2 u2; } pk;
#pragma unroll
    for (int c=0;c<4;++c) pk.us[c] = f2bf(acc[rr][c]);
    *(uint2*)&C[(size_t)(i0+tr*4+rr)*NN + j0 + tc*4] = pk.u2;
  }
}

// ---------- batched: per-row max/min over bf16 M0 ----------
__global__ __launch_bounds__(256) void rowstat_b(const unsigned short* __restrict__ Kbase,
                                                 float* __restrict__ rmax,
                                                 float* __restrict__ rmin)
{
  __shared__ float r1[4], r2[4];
  int m = blockIdx.y, i = blockIdx.x, t = threadIdx.x;
  const uint4* row = (const uint4*)(Kbase + ((size_t)m*NN + i)*NN);
  float mx=-3.4e38f, mn=3.4e38f;
#pragma unroll
  for (int s=0;s<2;++s){
    float e[8]; unpack8(row[t + s*256], e);
#pragma unroll
    for (int k=0;k<8;++k){ mx = fmaxf(mx,e[k]); mn = fminf(mn,e[k]); }
  }
  mx = waveMax(mx); mn = waveMin(mn);
  int lane = t & 63, wid = t >> 6;
  if (lane==0){ r1[wid]=mx; r2[wid]=mn; }
  __syncthreads();
  if (t==0){
    rmax[(size_t)m*NN+i] = fmaxf(fmaxf(r1[0],r1[1]),fmaxf(r1[2],r1[3]));
    rmin[(size_t)m*NN+i] = fminf(fminf(r2[0],r2[1]),fminf(r2[2],r2[3]));
  }
}

__global__ __launch_bounds__(256) void greduce_b(const float* __restrict__ rmax,
                                                 const float* __restrict__ rmin,
                                                 float* __restrict__ stat)
{
  __shared__ float r1[4], r2[4];
  int m = blockIdx.x, t = threadIdx.x;
  float mx=-3.4e38f, mn=3.4e38f;
  for (int i=t; i<NN; i+=256){
    mx = fmaxf(mx, rmax[(size_t)m*NN+i]);
    mn = fminf(mn, rmin[(size_t)m*NN+i]);
  }
  mx = waveMax(mx); mn = waveMin(mn);
  int lane = t & 63, wid = t >> 6;
  if (lane==0){ r1[wid]=mx; r2[wid]=mn; }
  __syncthreads();
  if (t==0){
    float gmx = fmaxf(fmaxf(r1[0],r1[1]),fmaxf(r1[2],r1[3]));
    float gmn = fminf(fminf(r2[0],r2[1]),fminf(r2[2],r2[3]));
    stat[m*2]   = gmn;
    stat[m*2+1] = 1.f/(gmx-gmn);
  }
}

// ---------- batched in-place K = exp((M0 - rowmax)*scale); M output for finalm ----------
__global__ __launch_bounds__(256) void transform_b(unsigned short* __restrict__ Kbase,
                                                   const float* __restrict__ rmax,
                                                   const float* __restrict__ stat,
                                                   float* __restrict__ Mout, int finalm)
{
  int m = blockIdx.y;
  const float gmin = stat[m*2], scale = stat[m*2+1];
  uint4* Km = (uint4*)(Kbase + (size_t)m*NN*NN);
  const bool wM = (m==finalm) && (Mout != nullptr);
  const int total8 = (NN*NN)/8;
  for (int f = blockIdx.x*256 + threadIdx.x; f < total8; f += 256*256){
    int i = f >> 9;
    float rm = rmax[(size_t)m*NN + i];
    float e[8]; unpack8(Km[f], e);
    union { unsigned short us[8]; uint4 u4; } pk;
#pragma unroll
    for (int k=0;k<8;++k) pk.us[k] = f2bf(__expf((e[k]-rm)*scale));
    Km[f] = pk.u4;
    if (wM){
      float4 o1, o2;
      o1.x=(e[0]-gmin)*scale; o1.y=(e[1]-gmin)*scale; o1.z=(e[2]-gmin)*scale; o1.w=(e[3]-gmin)*scale;
      o2.x=(e[4]-gmin)*scale; o2.y=(e[5]-gmin)*scale; o2.z=(e[6]-gmin)*scale; o2.w=(e[7]-gmin)*scale;
      float4* mp = (float4*)(Mout + (size_t)f*8);
      mp[0]=o1; mp[1]=o2;
    }
  }
}

__global__ void ot_init_b(float* __restrict__ v, double* __restrict__ accd, int nmat)
{
  int g = blockIdx.x*256 + threadIdx.x;
  if (g < nmat*NN) v[g] = 1.f;
  if (g < nmat) accd[g] = 0.0;
}

// ---------- batched u_i = R/(K v)_i ----------
__global__ __launch_bounds__(256) void rowmv_b(const unsigned short* __restrict__ Kbase,
                                               const float* __restrict__ vv,
                                               float* __restrict__ uu)
{
  __shared__ float red[4];
  int m = blockIdx.y, i = blockIdx.x, t = threadIdx.x;
  const uint4* row = (const uint4*)(Kbase + ((size_t)m*NN + i)*NN);
  const float4* v4 = (const float4*)(vv + (size_t)m*NN);
  float s = 0.f;
#pragma unroll
  for (int ss=0;ss<2;++ss){
    int j8 = t + ss*256;
    uint4 kk = row[j8];
    float4 va = v4[j8*2], vb = v4[j8*2+1];
    s += bflo(kk.x)*va.x + bfhi(kk.x)*va.y + bflo(kk.y)*va.z + bfhi(kk.y)*va.w
       + bflo(kk.z)*vb.x + bfhi(kk.z)*vb.y + bflo(kk.w)*vb.z + bfhi(kk.w)*vb.w;
  }
  float tot = blkSum(s, red);
  if (t==0) uu[(size_t)m*NN + i] = RVAL / tot;
}

// ---------- batched column partials ----------
__global__ __launch_bounds__(256) void colpart_b(const unsigned short* __restrict__ Kbase,
                                                 const float* __restrict__ uu,
                                                 float* __restrict__ part)
{
  __shared__ float su[128];
  int m = blockIdx.z;
  int j = blockIdx.x*256 + threadIdx.x;
  int r0 = blockIdx.y*128;
  if (threadIdx.x < 128) su[threadIdx.x] = uu[(size_t)m*NN + r0 + threadIdx.x];
  __syncthreads();
  const unsigned short* Km = Kbase + (size_t)m*NN*NN;
  float s = 0.f;
#pragma unroll 4
  for (int ii=0; ii<128; ++ii)
    s += bf2f(Km[(size_t)(r0+ii)*NN + j]) * su[ii];
  part[((size_t)m*32 + blockIdx.y)*NN + j] = s;
}

__global__ __launch_bounds__(256) void colfin_b(const float* __restrict__ part,
                                                float* __restrict__ vv)
{
  int m = blockIdx.y;
  int j = blockIdx.x*256 + threadIdx.x;
  float s = 0.f;
#pragma unroll
  for (int b=0;b<32;++b) s += part[((size_t)m*32 + b)*NN + j];
  vv[(size_t)m*NN + j] = RVAL / s;
}

// ---------- fused final: y = Kv ; P = K v_j / y ; acc += ||P - I||^2 ----------
__global__ __launch_bounds__(256) void loss_b(const unsigned short* __restrict__ Kbase,
                                              const float* __restrict__ vv,
                                              double* __restrict__ accd,
                                              float* __restrict__ Pout, int finalm)
{
  __shared__ float red[4];
  int m = blockIdx.y, i = blockIdx.x, t = threadIdx.x;
  const uint4* row = (const uint4*)(Kbase + ((size_t)m*NN + i)*NN);
  const float4* v4 = (const float4*)(vv + (size_t)m*NN);
  float e[16], vr[16];
#pragma unroll
  for (int ss=0;ss<2;++ss){
    int j8 = t + ss*256;
    unpack8(row[j8], &e[ss*8]);
    float4 va = v4[j8*2], vb = v4[j8*2+1];
    vr[ss*8+0]=va.x; vr[ss*8+1]=va.y; vr[ss*8+2]=va.z; vr[ss*8+3]=va.w;
    vr[ss*8+4]=vb.x; vr[ss*8+5]=vb.y; vr[ss*8+6]=vb.z; vr[ss*8+7]=vb.w;
  }
  float s = 0.f;
#pragma unroll
  for (int k=0;k<16;++k) s += e[k]*vr[k];
  float y = blkSum(s, red);
  float invy = 1.f / y;
  const bool wp = (m==finalm) && (Pout != nullptr);
  float local = 0.f;
#pragma unroll
  for (int ss=0;ss<2;++ss){
    int j0 = (t + ss*256)*8;
    float p[8];
#pragma unroll
    for (int k=0;k<8;++k) p[k] = e[ss*8+k]*vr[ss*8+k]*invy;
    if (wp){
      float4 o1, o2;
      o1.x=p[0]; o1.y=p[1]; o1.z=p[2]; o1.w=p[3];
      o2.x=p[4]; o2.y=p[5]; o2.z=p[6]; o2.w=p[7];
      float4* pp = (float4*)(Pout + (size_t)i*NN + j0);
      pp[0]=o1; pp[1]=o2;
    }
#pragma unroll
    for (int k=0;k<8;++k){
      float d = p[k] - ((j0+k)==i ? 1.f : 0.f);
      local += d*d;
    }
  }
  float tot = blkSum(local, red);
  if (t==0) atomicAdd(&accd[m], (double)tot);
}

__global__ void lossfin(const double* __restrict__ acc, float* __restrict__ outslot)
{
  if (threadIdx.x==0) *outslot = (float)sqrt(*acc);
}

__global__ void sumloss(float* __restrict__ out)
{
  if (threadIdx.x==0) out[0] = out[1]+out[2]+out[3]+out[4];
}

extern "C" void kernel_launch(void* const* d_in, const int* in_sizes, int n_in,
                              void* d_out, int out_size, void* d_ws, size_t ws_size,
                              hipStream_t stream)
{
  (void)in_sizes; (void)n_in; (void)out_size;
  const float* f_s  = (const float*)d_in[1];
  const float* l_s  = (const float*)d_in[2];
  const float* f_t  = (const float*)d_in[3];
  const float* l_t  = (const float*)d_in[4];
  const float* W_es = (const float*)d_in[5];
  const float* b_es = (const float*)d_in[6];
  const float* W_et = (const float*)d_in[7];
  const float* b_et = (const float*)d_in[8];
  const float* W_gs = (const float*)d_in[9];
  const float* b_gs = (const float*)d_in[10];
  const float* W_gt = (const float*)d_in[11];
  const float* b_gt = (const float*)d_in[12];
  float* out = (float*)d_out;

  char* ws = (char*)d_ws;
  size_t off = 0;
  auto alloc = [&](size_t nbytes)->void*{
    off = (off + 255) & ~(size_t)255;
    void* p = ws + off; off += nbytes; return p;
  };
  double* accd = (double*)alloc(4*sizeof(double));
  float* f_es = (float*)alloc((size_t)NN*FF*4);
  float* f_et = (float*)alloc((size_t)NN*FF*4);
  float* f_gs = (float*)alloc((size_t)NN*FF*4);
  float* f_gt = (float*)alloc((size_t)NN*FF*4);
  float* S_s  = (float*)alloc((size_t)NN*CD*4);
  float* S_t  = (float*)alloc((size_t)NN*CD*4);
  float* w_s  = (float*)alloc(NN*4);
  float* w_t  = (float*)alloc(NN*4);
  int*   idx_s= (int*)alloc(NN*8*4);
  int*   idx_t= (int*)alloc(NN*8*4);
  float* rmax = (float*)alloc((size_t)4*NN*4);
  float* rmin = (float*)alloc((size_t)4*NN*4);
  float* stat = (float*)alloc(64);
  float* v    = (float*)alloc((size_t)4*NN*4);
  float* u    = (float*)alloc((size_t)4*NN*4);
  float* part = (float*)alloc((size_t)4*32*NN*4);
  off = (off + 255) & ~(size_t)255;
  unsigned short* Kb = (unsigned short*)(ws + off);
  size_t remain = (ws_size > off) ? ws_size - off : 0;
  const size_t matB = (size_t)NN*NN*2;           // 32 MB per bf16 matrix
  const int big = (remain >= 4*matB) ? 1 : 0;    // need 128 MB for 4-way batch

  // embed scratch aliases the Kb region (used strictly before knn/OT)
  float* epart = (float*)Kb;                                    // KS*4096*128*4 = 16 MB
  unsigned short* Wt0 = (unsigned short*)((char*)Kb + (size_t)KS*NN*FF*4);
  unsigned short* Wt1 = Wt0 + (size_t)FF*EK;                    // 2 MB each

  float* Pout_final = out + 5;
  float* Mout_final = out + 5 + (size_t)NN*NN;

  // ---- embeddings (MFMA split-K) ----
  transposeW<<<EK/64,256,0,stream>>>(W_es, Wt0);
  transposeW<<<EK/64,256,0,stream>>>(W_et, Wt1);
  embed_mfma<<<dim3(64,KS),256,0,stream>>>(f_s, Wt0, epart);
  reduce_l2<<<NN,128,0,stream>>>(epart, b_es, f_es);
  embed_mfma<<<dim3(64,KS),256,0,stream>>>(f_t, Wt1, epart);
  reduce_l2<<<NN,128,0,stream>>>(epart, b_et, f_et);

  // ---- knn path (uses Kb region as scratch for fp32 cos matrices) ----
  softmax_rows<<<NN,128,0,stream>>>(l_s, S_s, w_s);
  softmax_rows<<<NN,128,0,stream>>>(l_t, S_t, w_t);
  if (big) {
    float* D_s = (float*)Kb;
    float* D_t = (float*)(Kb + 2*(size_t)NN*NN);
    cos_gemm<<<dim3(64,64),256,0,stream>>>(S_s, w_s, D_s);
    cos_gemm<<<dim3(64,64),256,0,stream>>>(S_t, w_t, D_t);
    knn_select<<<NN,256,0,stream>>>(D_s, idx_s);
    knn_select<<<NN,256,0,stream>>>(D_t, idx_t);
  } else {
    float* Db = (float*)Kb;
    cos_gemm<<<dim3(64,64),256,0,stream>>>(S_s, w_s, Db);
    knn_select<<<NN,256,0,stream>>>(Db, idx_s);
    cos_gemm<<<dim3(64,64),256,0,stream>>>(S_t, w_t, Db);
    knn_select<<<NN,256,0,stream>>>(Db, idx_t);
  }
  encoder_kernel<<<NN,128,0,stream>>>(f_es, idx_s, W_gs, b_gs, f_gs);
  encoder_kernel<<<NN,128,0,stream>>>(f_et, idx_t, W_gt, b_gt, f_gt);

  // ---- batched OT ----
  const float* ftab[4] = { f_et, f_gt, f_et, f_gt };
  const float* fsab[4] = { f_es, f_es, f_gt, f_gs };
  const int slotab[4]  = { 1, 3, 4, 2 };

  auto run_batch = [&](int m0, int nmat, int finalm){
    for (int m=0;m<nmat;++m)
      gemm_btb<<<dim3(64,64),256,0,stream>>>(ftab[m0+m], fsab[m0+m], Kb + (size_t)m*NN*NN);
    rowstat_b<<<dim3(NN,nmat),256,0,stream>>>(Kb, rmax, rmin);
    greduce_b<<<nmat,256,0,stream>>>(rmax, rmin, stat);
    transform_b<<<dim3(256,nmat),256,0,stream>>>(Kb, rmax, stat,
        (finalm>=0)?Mout_final:(float*)nullptr, finalm);
    ot_init_b<<<(4*NN+255)/256,256,0,stream>>>(v, accd, nmat);
    for (int it=0; it<OT_ITERS; ++it){
      rowmv_b<<<dim3(NN,nmat),256,0,stream>>>(Kb, v, u);
      colpart_b<<<dim3(16,32,nmat),256,0,stream>>>(Kb, u, part);
      colfin_b<<<dim3(16,nmat),256,0,stream>>>(part, v);
    }
    loss_b<<<dim3(NN,nmat),256,0,stream>>>(Kb, v, accd,
        (finalm>=0)?Pout_final:(float*)nullptr, finalm);
    for (int m=0;m<nmat;++m)
      lossfin<<<1,1,0,stream>>>(accd+m, out + slotab[m0+m]);
  };

  if (big) {
    run_batch(0, 4, 3);
  } else {
    run_batch(0, 2, -1);
    run_batch(2, 2, 1);
  }

  sumloss<<<1,1,0,stream>>>(out);
}

// Round 5
// 1167.216 us; speedup vs baseline: 6.9367x; 1.5992x over previous
//
#include <hip/hip_runtime.h>
#include <math.h>

#define NN 4096
#define FF 128
#define CD 100
#define OT_ITERS 20
#define RVAL (1.0f/4096.0f)
#define EK 8192
#define KS 8
#define CHUNK 16          // rows per sink_fused block -> 256 chunks
#define NCH 256

typedef unsigned int uint;
typedef __attribute__((ext_vector_type(8))) short bf16x8;
typedef __attribute__((ext_vector_type(4))) float f32x4;

// ---------- bf16 helpers ----------
__device__ __forceinline__ float bflo(uint u){ return __uint_as_float(u << 16); }
__device__ __forceinline__ float bfhi(uint u){ return __uint_as_float(u & 0xFFFF0000u); }
__device__ __forceinline__ float bf2f(unsigned short s){ return __uint_as_float((uint)s << 16); }
__device__ __forceinline__ unsigned short f2bf(float x){
  uint u = __float_as_uint(x);
  u += 0x7FFFu + ((u >> 16) & 1u);
  return (unsigned short)(u >> 16);
}
__device__ __forceinline__ void unpack8(uint4 kk, float* e){
  e[0]=bflo(kk.x); e[1]=bfhi(kk.x); e[2]=bflo(kk.y); e[3]=bfhi(kk.y);
  e[4]=bflo(kk.z); e[5]=bfhi(kk.z); e[6]=bflo(kk.w); e[7]=bfhi(kk.w);
}
__device__ __forceinline__ uint4 pack8(const float* e){
  union { unsigned short us[8]; uint4 u4; } pk;
#pragma unroll
  for (int k=0;k<8;++k) pk.us[k]=f2bf(e[k]);
  return pk.u4;
}

// ---------- wave/block reduce helpers (wave = 64) ----------
__device__ __forceinline__ float waveSum(float v){
#pragma unroll
  for (int o=32;o>0;o>>=1) v += __shfl_down(v,o);
  return v;
}
__device__ __forceinline__ float waveMax(float v){
#pragma unroll
  for (int o=32;o>0;o>>=1) v = fmaxf(v,__shfl_down(v,o));
  return v;
}
__device__ __forceinline__ float waveMin(float v){
#pragma unroll
  for (int o=32;o>0;o>>=1) v = fminf(v,__shfl_down(v,o));
  return v;
}
__device__ __forceinline__ float blkSum(float v, float* red){
  v = waveSum(v);
  if ((threadIdx.x&63)==0) red[threadIdx.x>>6] = v;
  __syncthreads();
  float r = red[0]+red[1]+red[2]+red[3];
  __syncthreads();
  return r;
}

// ---------- W transpose+convert: Wt[n][k] bf16 from W[k][n] fp32 ----------
__global__ __launch_bounds__(256) void transposeW(const float* __restrict__ W,
                                                  unsigned short* __restrict__ Wt)
{
  __shared__ unsigned short T[128][72];
  const int k0 = blockIdx.x*64, tid = threadIdx.x;
#pragma unroll
  for (int it=0; it<8; ++it){
    int f = tid + it*256;
    int r = f >> 5, c4 = f & 31;
    float4 v = *(const float4*)&W[(size_t)(k0+r)*FF + c4*4];
    T[c4*4+0][r]=f2bf(v.x); T[c4*4+1][r]=f2bf(v.y);
    T[c4*4+2][r]=f2bf(v.z); T[c4*4+3][r]=f2bf(v.w);
  }
  __syncthreads();
#pragma unroll
  for (int it=0; it<4; ++it){
    int f = tid + it*256;
    int n = f >> 3, c8 = f & 7;
    *(uint4*)&Wt[(size_t)n*EK + k0 + c8*8] = *(uint4*)&T[n][c8*8];
  }
}

// ---------- MFMA embed GEMM (split-K): part[ks][4096][128] ----------
__global__ __launch_bounds__(256) void embed_mfma(const float* __restrict__ A,
                                                  const unsigned short* __restrict__ Wt,
                                                  float* __restrict__ part)
{
  __shared__ unsigned short Al[64][72];
  __shared__ unsigned short Wl[128][72];
  const int tid = threadIdx.x;
  const int m0 = blockIdx.x * 64;
  const int kc = blockIdx.y * (EK/KS);
  const int w = tid >> 6, l = tid & 63;
  const int wr = w >> 1, wc = w & 1;
  const int lrow = l & 15, lk = (l >> 4) * 8;
  f32x4 acc[2][4];
#pragma unroll
  for (int mi=0;mi<2;++mi)
#pragma unroll
    for (int ni=0;ni<4;++ni) acc[mi][ni] = (f32x4){0.f,0.f,0.f,0.f};

  for (int k0 = kc; k0 < kc + EK/KS; k0 += 64) {
#pragma unroll
    for (int it = 0; it < 4; ++it) {
      int f = tid + it*256;
      int r = f >> 4, c4 = f & 15;
      float4 a4 = *(const float4*)&A[(size_t)(m0+r)*EK + k0 + c4*4];
      union { unsigned short us[4]; uint2 u2; } pk;
      pk.us[0]=f2bf(a4.x); pk.us[1]=f2bf(a4.y); pk.us[2]=f2bf(a4.z); pk.us[3]=f2bf(a4.w);
      *(uint2*)&Al[r][c4*4] = pk.u2;
    }
#pragma unroll
    for (int it = 0; it < 4; ++it) {
      int f = tid + it*256;
      int r = f >> 3, c8 = f & 7;
      *(uint4*)&Wl[r][c8*8] = *(const uint4*)&Wt[(size_t)r*EK + k0 + c8*8];
    }
    __syncthreads();
#pragma unroll
    for (int ksub = 0; ksub < 2; ++ksub) {
      bf16x8 af[2], bfr[4];
#pragma unroll
      for (int mi=0;mi<2;++mi) af[mi] = *(bf16x8*)&Al[wr*32+mi*16+lrow][ksub*32+lk];
#pragma unroll
      for (int ni=0;ni<4;++ni) bfr[ni] = *(bf16x8*)&Wl[wc*64+ni*16+lrow][ksub*32+lk];
#pragma unroll
      for (int mi=0;mi<2;++mi)
#pragma unroll
        for (int ni=0;ni<4;++ni)
          acc[mi][ni] = __builtin_amdgcn_mfma_f32_16x16x32_bf16(af[mi], bfr[ni], acc[mi][ni], 0,0,0);
    }
    __syncthreads();
  }
#pragma unroll
  for (int mi=0;mi<2;++mi)
#pragma unroll
    for (int ni=0;ni<4;++ni)
#pragma unroll
      for (int r=0;r<4;++r) {
        int row = m0 + wr*32 + mi*16 + (l>>4)*4 + r;
        int col = wc*64 + ni*16 + lrow;
        part[((size_t)blockIdx.y*NN + row)*FF + col] = acc[mi][ni][r];
      }
}

// ---------- reduce split-K partials + bias + l2norm -> fp32 and bf16 ----------
__global__ __launch_bounds__(128) void reduce_l2(const float* __restrict__ part,
                                                 const float* __restrict__ bias,
                                                 float* __restrict__ out,
                                                 unsigned short* __restrict__ outb)
{
  __shared__ float red[2];
  int i = blockIdx.x, t = threadIdx.x;
  float s = bias[t];
#pragma unroll
  for (int ks=0; ks<KS; ++ks) s += part[((size_t)ks*NN + i)*FF + t];
  float q = waveSum(s*s);
  if ((t&63)==0) red[t>>6]=q;
  __syncthreads();
  float val = s / sqrtf(red[0]+red[1]);
  out[(size_t)i*FF+t] = val;
  outb[(size_t)i*FF+t] = f2bf(val);
}

// ---------- softmax rows of l[4096x100] -> S, w = ||S_row|| ----------
__global__ __launch_bounds__(128) void softmax_rows(const float* __restrict__ l,
                                                    float* __restrict__ S,
                                                    float* __restrict__ w)
{
  __shared__ float sm[2], ss[2], sq[2];
  int i = blockIdx.x, t = threadIdx.x;
  int lane = t & 63, wid = t >> 6;
  float x = (t < CD) ? l[(size_t)i*CD + t] : -3.4e38f;
  float m = waveMax(x);
  if (lane==0) sm[wid]=m;
  __syncthreads();
  m = fmaxf(sm[0], sm[1]);
  float e = (t < CD) ? __expf(x - m) : 0.f;
  float s = waveSum(e);
  if (lane==0) ss[wid]=s;
  __syncthreads();
  float tot = ss[0]+ss[1];
  float sv = e / tot;
  if (t < CD) S[(size_t)i*CD + t] = sv;
  float q = waveSum(sv*sv);
  if (lane==0) sq[wid]=q;
  __syncthreads();
  if (t==0) w[i] = sqrtf(sq[0]+sq[1]);
}

// ---------- cos matrix: D[i][j] = (S_i . S_j)/max(w_i w_j, eps), diag = -2 ----------
__global__ __launch_bounds__(256) void cos_gemm(const float* __restrict__ S,
                                                const float* __restrict__ w,
                                                float* __restrict__ D)
{
  __shared__ float As[64][108];
  __shared__ float Bs[100][68];
  const int tid = threadIdx.x;
  const int tc = tid & 15, tr = tid >> 4;
  const int i0 = blockIdx.y*64, j0 = blockIdx.x*64;
  for (int f = tid; f < 64*25; f += 256){
    int r = f/25, c4 = f%25;
    *(float4*)&As[r][c4*4] = *(const float4*)&S[(size_t)(i0+r)*CD + c4*4];
  }
  for (int f = tid; f < 64*25; f += 256){
    int r = f/25, c4 = f%25;
    float4 bv = *(const float4*)&S[(size_t)(j0+r)*CD + c4*4];
    Bs[c4*4+0][r]=bv.x; Bs[c4*4+1][r]=bv.y; Bs[c4*4+2][r]=bv.z; Bs[c4*4+3][r]=bv.w;
  }
  __syncthreads();
  float acc[4][4];
#pragma unroll
  for (int a=0;a<4;++a)
#pragma unroll
    for (int b=0;b<4;++b) acc[a][b]=0.f;
  for (int kk=0; kk<100; kk+=4){
    float a[4][4];
#pragma unroll
    for (int q=0;q<4;++q) *(float4*)a[q] = *(const float4*)&As[tr*4+q][kk];
#pragma unroll
    for (int t4=0;t4<4;++t4){
      float4 b = *(const float4*)&Bs[kk+t4][tc*4];
#pragma unroll
      for (int rr=0;rr<4;++rr){
        float av = a[rr][t4];
        acc[rr][0] += av*b.x; acc[rr][1] += av*b.y;
        acc[rr][2] += av*b.z; acc[rr][3] += av*b.w;
      }
    }
  }
  float wi[4], wj[4];
#pragma unroll
  for (int q=0;q<4;++q){ wi[q] = w[i0+tr*4+q]; wj[q] = w[j0+tc*4+q]; }
#pragma unroll
  for (int rr=0;rr<4;++rr){
    int i = i0+tr*4+rr;
    float4 o;
    float* op = (float*)&o;
#pragma unroll
    for (int cc=0;cc<4;++cc){
      int j = j0+tc*4+cc;
      float val = acc[rr][cc] / fmaxf(wi[rr]*wj[cc], 1e-7f);
      op[cc] = (i==j) ? -2.f : val;
    }
    *(float4*)&D[(size_t)i*NN + j0 + tc*4] = o;
  }
}

// ---------- top-7 select per row of D; idx[i][0] = i ----------
__global__ __launch_bounds__(256) void knn_select(const float* __restrict__ D,
                                                  int* __restrict__ idx)
{
  __shared__ float redv[256];
  __shared__ int   redi[256];
  int i = blockIdx.x, tid = threadIdx.x;
  float bv[7]; int bi[7];
#pragma unroll
  for (int m=0;m<7;++m){ bv[m]=-3.4e38f; bi[m]=-1; }
  const float4* row4 = (const float4*)&D[(size_t)i*NN];
#pragma unroll
  for (int s=0;s<4;++s){
    int j4 = tid + s*256;
    float4 vv = row4[j4];
    float cv[4] = {vv.x, vv.y, vv.z, vv.w};
#pragma unroll
    for (int q=0;q<4;++q){
      if (cv[q] > bv[6]) {
        int m = 6;
        while (m > 0 && cv[q] > bv[m-1]) { bv[m]=bv[m-1]; bi[m]=bi[m-1]; --m; }
        bv[m]=cv[q]; bi[m]=j4*4+q;
      }
    }
  }
  if (tid==0) idx[(size_t)i*8] = i;
  for (int m=0;m<7;++m) {
    redv[tid]=bv[0]; redi[tid]=tid;
    __syncthreads();
    for (int s=128;s>=1;s>>=1) {
      if (tid < s) {
        if (redv[tid+s] > redv[tid]) { redv[tid]=redv[tid+s]; redi[tid]=redi[tid+s]; }
      }
      __syncthreads();
    }
    int wt = redi[0];
    if (tid == wt) {
      idx[(size_t)i*8 + 1 + m] = bi[0];
#pragma unroll
      for (int q=0;q<6;++q){ bv[q]=bv[q+1]; bi[q]=bi[q+1]; }
      bv[6]=-3.4e38f; bi[6]=-1;
    }
    __syncthreads();
  }
}

// ---------- encoder: outb = bf16(l2norm(concat(h, mean(h[idx])) @ W + b)) ----------
__global__ __launch_bounds__(128) void encoder_kernel(const float* __restrict__ h,
                                                      const int* __restrict__ idx,
                                                      const float* __restrict__ W,
                                                      const float* __restrict__ bias,
                                                      unsigned short* __restrict__ outb)
{
  __shared__ float hin[256];
  __shared__ float sred[2];
  int i = blockIdx.x, t = threadIdx.x;
  float hv = h[(size_t)i*FF + t];
  float agg = 0.f;
#pragma unroll
  for (int m=0;m<8;++m) agg += h[(size_t)idx[i*8+m]*FF + t];
  agg *= 0.125f;
  hin[t] = hv; hin[FF + t] = agg;
  __syncthreads();
  float acc = bias[t];
  for (int k=0;k<256;++k) acc += hin[k] * W[(size_t)k*FF + t];
  float s = waveSum(acc*acc);
  int lane = t & 63, wid = t >> 6;
  if (lane==0) sred[wid]=s;
  __syncthreads();
  float tot = sred[0]+sred[1];
  outb[(size_t)i*FF + t] = f2bf(acc / sqrtf(tot));
}

// ---------- MFMA: C[4096x4096] bf16 = A bf16 [4096x128] @ B^T ----------
__global__ __launch_bounds__(256) void gemm_btb_mfma(const unsigned short* __restrict__ A,
                                                     const unsigned short* __restrict__ B,
                                                     unsigned short* __restrict__ C)
{
  __shared__ unsigned short Al[64][136];
  __shared__ unsigned short Bl[64][136];
  const int tid = threadIdx.x;
  const int i0 = blockIdx.y*64, j0 = blockIdx.x*64;
#pragma unroll
  for (int it=0; it<4; ++it){
    int f = tid + it*256;
    int r = f >> 4, c8 = f & 15;
    *(uint4*)&Al[r][c8*8] = *(const uint4*)&A[(size_t)(i0+r)*FF + c8*8];
    *(uint4*)&Bl[r][c8*8] = *(const uint4*)&B[(size_t)(j0+r)*FF + c8*8];
  }
  __syncthreads();
  const int w = tid>>6, l = tid&63;
  const int wr = w>>1, wc = w&1;
  const int lrow = l&15, lk = (l>>4)*8;
  f32x4 acc[2][2];
#pragma unroll
  for (int mi=0;mi<2;++mi)
#pragma unroll
    for (int ni=0;ni<2;++ni) acc[mi][ni] = (f32x4){0.f,0.f,0.f,0.f};
#pragma unroll
  for (int ks=0; ks<4; ++ks){
    bf16x8 af[2], bfm[2];
#pragma unroll
    for (int mi=0;mi<2;++mi) af[mi] = *(bf16x8*)&Al[wr*32+mi*16+lrow][ks*32+lk];
#pragma unroll
    for (int ni=0;ni<2;++ni) bfm[ni] = *(bf16x8*)&Bl[wc*32+ni*16+lrow][ks*32+lk];
#pragma unroll
    for (int mi=0;mi<2;++mi)
#pragma unroll
      for (int ni=0;ni<2;++ni)
        acc[mi][ni] = __builtin_amdgcn_mfma_f32_16x16x32_bf16(af[mi], bfm[ni], acc[mi][ni], 0,0,0);
  }
  __syncthreads();
  unsigned short (*Cl)[72] = (unsigned short(*)[72])&Al[0][0];
#pragma unroll
  for (int mi=0;mi<2;++mi)
#pragma unroll
    for (int ni=0;ni<2;++ni)
#pragma unroll
      for (int r=0;r<4;++r){
        int row = wr*32 + mi*16 + (l>>4)*4 + r;
        int col = wc*32 + ni*16 + lrow;
        Cl[row][col] = f2bf(acc[mi][ni][r]);
      }
  __syncthreads();
#pragma unroll
  for (int it=0; it<2; ++it){
    int f = tid + it*256;
    int r = f >> 3, c8 = f & 7;
    *(uint4*)&C[(size_t)(i0+r)*NN + j0 + c8*8] = *(uint4*)&Cl[r][c8*8];
  }
}

// ---------- batched: per-row max/min over bf16 M0 ----------
__global__ __launch_bounds__(256) void rowstat_b(const unsigned short* __restrict__ Kbase,
                                                 float* __restrict__ rmax,
                                                 float* __restrict__ rmin)
{
  __shared__ float r1[4], r2[4];
  int m = blockIdx.y, i = blockIdx.x, t = threadIdx.x;
  const uint4* row = (const uint4*)(Kbase + ((size_t)m*NN + i)*NN);
  float mx=-3.4e38f, mn=3.4e38f;
#pragma unroll
  for (int s=0;s<2;++s){
    float e[8]; unpack8(row[t + s*256], e);
#pragma unroll
    for (int k=0;k<8;++k){ mx = fmaxf(mx,e[k]); mn = fminf(mn,e[k]); }
  }
  mx = waveMax(mx); mn = waveMin(mn);
  int lane = t & 63, wid = t >> 6;
  if (lane==0){ r1[wid]=mx; r2[wid]=mn; }
  __syncthreads();
  if (t==0){
    rmax[(size_t)m*NN+i] = fmaxf(fmaxf(r1[0],r1[1]),fmaxf(r1[2],r1[3]));
    rmin[(size_t)m*NN+i] = fminf(fminf(r2[0],r2[1]),fminf(r2[2],r2[3]));
  }
}

__global__ __launch_bounds__(256) void greduce_b(const float* __restrict__ rmax,
                                                 const float* __restrict__ rmin,
                                                 float* __restrict__ stat)
{
  __shared__ float r1[4], r2[4];
  int m = blockIdx.x, t = threadIdx.x;
  float mx=-3.4e38f, mn=3.4e38f;
  for (int i=t; i<NN; i+=256){
    mx = fmaxf(mx, rmax[(size_t)m*NN+i]);
    mn = fminf(mn, rmin[(size_t)m*NN+i]);
  }
  mx = waveMax(mx); mn = waveMin(mn);
  int lane = t & 63, wid = t >> 6;
  if (lane==0){ r1[wid]=mx; r2[wid]=mn; }
  __syncthreads();
  if (t==0){
    float gmx = fmaxf(fmaxf(r1[0],r1[1]),fmaxf(r1[2],r1[3]));
    float gmn = fminf(fminf(r2[0],r2[1]),fminf(r2[2],r2[3]));
    stat[m*2]   = gmn;
    stat[m*2+1] = 1.f/(gmx-gmn);
  }
}

// ---------- batched in-place K = exp((M0 - rowmax)*scale); M output for finalm ----------
__global__ __launch_bounds__(256) void transform_b(unsigned short* __restrict__ Kbase,
                                                   const float* __restrict__ rmax,
                                                   const float* __restrict__ stat,
                                                   float* __restrict__ Mout, int finalm)
{
  int m = blockIdx.y;
  const float gmin = stat[m*2], scale = stat[m*2+1];
  uint4* Km = (uint4*)(Kbase + (size_t)m*NN*NN);
  const bool wM = (m==finalm) && (Mout != nullptr);
  const int total8 = (NN*NN)/8;
  for (int f = blockIdx.x*256 + threadIdx.x; f < total8; f += 256*256){
    int i = f >> 9;
    float rm = rmax[(size_t)m*NN + i];
    float e[8]; unpack8(Km[f], e);
    union { unsigned short us[8]; uint4 u4; } pk;
#pragma unroll
    for (int k=0;k<8;++k) pk.us[k] = f2bf(__expf((e[k]-rm)*scale));
    Km[f] = pk.u4;
    if (wM){
      float4 o1, o2;
      o1.x=(e[0]-gmin)*scale; o1.y=(e[1]-gmin)*scale; o1.z=(e[2]-gmin)*scale; o1.w=(e[3]-gmin)*scale;
      o2.x=(e[4]-gmin)*scale; o2.y=(e[5]-gmin)*scale; o2.z=(e[6]-gmin)*scale; o2.w=(e[7]-gmin)*scale;
      float4* mp = (float4*)(Mout + (size_t)f*8);
      mp[0]=o1; mp[1]=o2;
    }
  }
}

__global__ void ot_init_b(float* __restrict__ v, int nmat)
{
  int g = blockIdx.x*256 + threadIdx.x;
  if (g < nmat*NN) v[g] = 1.f;
}

// ---------- fused sinkhorn iteration: one K pass ----------
// block owns CHUNK=16 rows; per row: u_r = R/(row.v); colacc += row*u_r (registers)
__global__ __launch_bounds__(256) void sink_fused(const unsigned short* __restrict__ Kbase,
                                                  const float* __restrict__ vv,
                                                  unsigned short* __restrict__ part)
{
  __shared__ float red[4];
  const int m = blockIdx.y, b = blockIdx.x, t = threadIdx.x;
  const int i0 = b*CHUNK;
  const unsigned short* Km = Kbase + (size_t)m*NN*NN;
  const float4* v4 = (const float4*)(vv + (size_t)m*NN);
  float vs[16];
  {
    float4 a = v4[t*2], bq = v4[t*2+1];
    vs[0]=a.x; vs[1]=a.y; vs[2]=a.z; vs[3]=a.w;
    vs[4]=bq.x; vs[5]=bq.y; vs[6]=bq.z; vs[7]=bq.w;
    float4 c = v4[512+t*2], d = v4[512+t*2+1];
    vs[8]=c.x; vs[9]=c.y; vs[10]=c.z; vs[11]=d.x-d.x+c.w;  // c.w
    vs[11]=c.w; vs[12]=d.x; vs[13]=d.y; vs[14]=d.z; vs[15]=d.w;
  }
  float colacc[16];
#pragma unroll
  for (int k=0;k<16;++k) colacc[k]=0.f;
  for (int r=0;r<CHUNK;++r){
    const uint4* row = (const uint4*)(Km + (size_t)(i0+r)*NN);
    uint4 k0 = row[t], k1 = row[256+t];
    float e[16]; unpack8(k0, e); unpack8(k1, e+8);
    float dot = 0.f;
#pragma unroll
    for (int k=0;k<16;++k) dot += e[k]*vs[k];
    float rowsum = blkSum(dot, red);
    float ur = RVAL / rowsum;
#pragma unroll
    for (int k=0;k<16;++k) colacc[k] += e[k]*ur;
  }
  unsigned short* prow = part + ((size_t)m*NCH + b)*NN;
  ((uint4*)prow)[t]     = pack8(colacc);
  ((uint4*)prow)[256+t] = pack8(colacc+8);
}

// ---------- column finish: v[j] = R / sum_b part[m][b][j] ----------
// grid (32, nmat); block covers 128 cols; 2-level LDS reduce over 256 chunks
__global__ __launch_bounds__(256) void colfin_b(const unsigned short* __restrict__ part,
                                                float* __restrict__ vv)
{
  __shared__ float lds[16][16][8];
  const int m = blockIdx.y, bx = blockIdx.x, t = threadIdx.x;
  const int g = t & 15;          // uint4-group within 128 cols (16 groups)
  const int tq = t >> 4;         // chunk-thread (16)
  const uint4* pb = (const uint4*)(part + (size_t)m*NCH*NN);
  float acc[8];
#pragma unroll
  for (int k=0;k<8;++k) acc[k]=0.f;
#pragma unroll 4
  for (int s=0;s<16;++s){
    int b = tq + s*16;
    float e[8]; unpack8(pb[(size_t)b*512 + bx*16 + g], e);
#pragma unroll
    for (int k=0;k<8;++k) acc[k] += e[k];
  }
#pragma unroll
  for (int k=0;k<8;++k) lds[tq][g][k] = acc[k];
  __syncthreads();
  if (t < 128){
    int gg = t >> 3, c = t & 7;
    float s = 0.f;
#pragma unroll
    for (int q=0;q<16;++q) s += lds[q][gg][c];
    vv[(size_t)m*NN + bx*128 + gg*8 + c] = RVAL / s;
  }
}

// ---------- final: y = Kv ; P = K v_j / y ; per-block loss partial (no atomics) ----------
__global__ __launch_bounds__(256) void loss2_b(const unsigned short* __restrict__ Kbase,
                                               const float* __restrict__ vv,
                                               float* __restrict__ accf,
                                               float* __restrict__ Pout, int finalm)
{
  __shared__ float red[4];
  int m = blockIdx.y, i = blockIdx.x, t = threadIdx.x;
  const uint4* row = (const uint4*)(Kbase + ((size_t)m*NN + i)*NN);
  const float4* v4 = (const float4*)(vv + (size_t)m*NN);
  float e[16], vr[16];
#pragma unroll
  for (int ss=0;ss<2;++ss){
    int j8 = t + ss*256;
    unpack8(row[j8], &e[ss*8]);
    float4 va = v4[j8*2], vb = v4[j8*2+1];
    vr[ss*8+0]=va.x; vr[ss*8+1]=va.y; vr[ss*8+2]=va.z; vr[ss*8+3]=va.w;
    vr[ss*8+4]=vb.x; vr[ss*8+5]=vb.y; vr[ss*8+6]=vb.z; vr[ss*8+7]=vb.w;
  }
  float s = 0.f;
#pragma unroll
  for (int k=0;k<16;++k) s += e[k]*vr[k];
  float y = blkSum(s, red);
  float invy = 1.f / y;
  const bool wp = (m==finalm) && (Pout != nullptr);
  float local = 0.f;
#pragma unroll
  for (int ss=0;ss<2;++ss){
    int j0 = (t + ss*256)*8;
    float p[8];
#pragma unroll
    for (int k=0;k<8;++k) p[k] = e[ss*8+k]*vr[ss*8+k]*invy;
    if (wp){
      float4 o1, o2;
      o1.x=p[0]; o1.y=p[1]; o1.z=p[2]; o1.w=p[3];
      o2.x=p[4]; o2.y=p[5]; o2.z=p[6]; o2.w=p[7];
      float4* pp = (float4*)(Pout + (size_t)i*NN + j0);
      pp[0]=o1; pp[1]=o2;
    }
#pragma unroll
    for (int k=0;k<8;++k){
      float d = p[k] - ((j0+k)==i ? 1.f : 0.f);
      local += d*d;
    }
  }
  float tot = blkSum(local, red);
  if (t==0) accf[(size_t)m*NN + i] = tot;
}

// ---------- deterministic loss reduce: out = sqrt(sum accf[0..NN)) ----------
__global__ __launch_bounds__(256) void lossfin2(const float* __restrict__ accf,
                                                float* __restrict__ outslot)
{
  __shared__ float red[4];
  int t = threadIdx.x;
  float s = 0.f;
#pragma unroll
  for (int q=0;q<16;++q) s += accf[t + q*256];
  float tot = blkSum(s, red);
  if (t==0) *outslot = sqrtf(tot);
}

__global__ void sumloss(float* __restrict__ out)
{
  if (threadIdx.x==0) out[0] = out[1]+out[2]+out[3]+out[4];
}

extern "C" void kernel_launch(void* const* d_in, const int* in_sizes, int n_in,
                              void* d_out, int out_size, void* d_ws, size_t ws_size,
                              hipStream_t stream)
{
  (void)in_sizes; (void)n_in; (void)out_size;
  const float* f_s  = (const float*)d_in[1];
  const float* l_s  = (const float*)d_in[2];
  const float* f_t  = (const float*)d_in[3];
  const float* l_t  = (const float*)d_in[4];
  const float* W_es = (const float*)d_in[5];
  const float* b_es = (const float*)d_in[6];
  const float* W_et = (const float*)d_in[7];
  const float* b_et = (const float*)d_in[8];
  const float* W_gs = (const float*)d_in[9];
  const float* b_gs = (const float*)d_in[10];
  const float* W_gt = (const float*)d_in[11];
  const float* b_gt = (const float*)d_in[12];
  float* out = (float*)d_out;

  char* ws = (char*)d_ws;
  size_t off = 0;
  auto alloc = [&](size_t nbytes)->void*{
    off = (off + 255) & ~(size_t)255;
    void* p = ws + off; off += nbytes; return p;
  };
  float* f_es = (float*)alloc((size_t)NN*FF*4);
  float* f_et = (float*)alloc((size_t)NN*FF*4);
  unsigned short* f_esb = (unsigned short*)alloc((size_t)NN*FF*2);
  unsigned short* f_etb = (unsigned short*)alloc((size_t)NN*FF*2);
  unsigned short* f_gsb = (unsigned short*)alloc((size_t)NN*FF*2);
  unsigned short* f_gtb = (unsigned short*)alloc((size_t)NN*FF*2);
  float* S_s  = (float*)alloc((size_t)NN*CD*4);
  float* S_t  = (float*)alloc((size_t)NN*CD*4);
  float* w_s  = (float*)alloc(NN*4);
  float* w_t  = (float*)alloc(NN*4);
  int*   idx_s= (int*)alloc(NN*8*4);
  int*   idx_t= (int*)alloc(NN*8*4);
  float* rmax = (float*)alloc((size_t)4*NN*4);
  float* rmin = (float*)alloc((size_t)4*NN*4);
  float* stat = (float*)alloc(64);
  float* v    = (float*)alloc((size_t)4*NN*4);
  float* accf = (float*)alloc((size_t)4*NN*4);
  unsigned short* part = (unsigned short*)alloc((size_t)4*NCH*NN*2);  // 8 MB
  off = (off + 255) & ~(size_t)255;
  unsigned short* Kb = (unsigned short*)(ws + off);
  size_t remain = (ws_size > off) ? ws_size - off : 0;
  const size_t matB = (size_t)NN*NN*2;
  const int big = (remain >= 4*matB) ? 1 : 0;

  // embed scratch aliases the Kb region (used strictly before knn/OT)
  float* epart = (float*)Kb;                                    // 16 MB
  unsigned short* Wt0 = (unsigned short*)((char*)Kb + (size_t)KS*NN*FF*4);
  unsigned short* Wt1 = Wt0 + (size_t)FF*EK;

  float* Pout_final = out + 5;
  float* Mout_final = out + 5 + (size_t)NN*NN;

  // ---- embeddings (MFMA split-K) ----
  transposeW<<<EK/64,256,0,stream>>>(W_es, Wt0);
  transposeW<<<EK/64,256,0,stream>>>(W_et, Wt1);
  embed_mfma<<<dim3(64,KS),256,0,stream>>>(f_s, Wt0, epart);
  reduce_l2<<<NN,128,0,stream>>>(epart, b_es, f_es, f_esb);
  embed_mfma<<<dim3(64,KS),256,0,stream>>>(f_t, Wt1, epart);
  reduce_l2<<<NN,128,0,stream>>>(epart, b_et, f_et, f_etb);

  // ---- knn path ----
  softmax_rows<<<NN,128,0,stream>>>(l_s, S_s, w_s);
  softmax_rows<<<NN,128,0,stream>>>(l_t, S_t, w_t);
  if (big) {
    float* D_s = (float*)Kb;
    float* D_t = (float*)(Kb + 2*(size_t)NN*NN);
    cos_gemm<<<dim3(64,64),256,0,stream>>>(S_s, w_s, D_s);
    cos_gemm<<<dim3(64,64),256,0,stream>>>(S_t, w_t, D_t);
    knn_select<<<NN,256,0,stream>>>(D_s, idx_s);
    knn_select<<<NN,256,0,stream>>>(D_t, idx_t);
  } else {
    float* Db = (float*)Kb;
    cos_gemm<<<dim3(64,64),256,0,stream>>>(S_s, w_s, Db);
    knn_select<<<NN,256,0,stream>>>(Db, idx_s);
    cos_gemm<<<dim3(64,64),256,0,stream>>>(S_t, w_t, Db);
    knn_select<<<NN,256,0,stream>>>(Db, idx_t);
  }
  encoder_kernel<<<NN,128,0,stream>>>(f_es, idx_s, W_gs, b_gs, f_gsb);
  encoder_kernel<<<NN,128,0,stream>>>(f_et, idx_t, W_gt, b_gt, f_gtb);

  // ---- batched OT ----
  const unsigned short* ftab[4] = { f_etb, f_gtb, f_etb, f_gtb };
  const unsigned short* fsab[4] = { f_esb, f_esb, f_gtb, f_gsb };
  const int slotab[4]  = { 1, 3, 4, 2 };

  auto run_batch = [&](int m0, int nmat, int finalm){
    for (int m=0;m<nmat;++m)
      gemm_btb_mfma<<<dim3(64,64),256,0,stream>>>(ftab[m0+m], fsab[m0+m], Kb + (size_t)m*NN*NN);
    rowstat_b<<<dim3(NN,nmat),256,0,stream>>>(Kb, rmax, rmin);
    greduce_b<<<nmat,256,0,stream>>>(rmax, rmin, stat);
    transform_b<<<dim3(256,nmat),256,0,stream>>>(Kb, rmax, stat,
        (finalm>=0)?Mout_final:(float*)nullptr, finalm);
    ot_init_b<<<(4*NN+255)/256,256,0,stream>>>(v, nmat);
    for (int it=0; it<OT_ITERS; ++it){
      sink_fused<<<dim3(NCH,nmat),256,0,stream>>>(Kb, v, part);
      colfin_b<<<dim3(32,nmat),256,0,stream>>>(part, v);
    }
    loss2_b<<<dim3(NN,nmat),256,0,stream>>>(Kb, v, accf,
        (finalm>=0)?Pout_final:(float*)nullptr, finalm);
    for (int m=0;m<nmat;++m)
      lossfin2<<<1,256,0,stream>>>(accf + (size_t)m*NN, out + slotab[m0+m]);
  };

  if (big) {
    run_batch(0, 4, 3);
  } else {
    run_batch(0, 2, -1);
    run_batch(2, 2, 1);
  }

  sumloss<<<1,1,0,stream>>>(out);
}